// Round 8
// baseline (664.934 us; speedup 1.0000x reference)
//
#include <hip/hip_runtime.h>
#include <math.h>

// Problem constants
#define NN 8192
#define INS 512
#define FEAT 128

typedef unsigned short ush;
typedef short bf16x8 __attribute__((ext_vector_type(8)));
typedef float f32x4 __attribute__((ext_vector_type(4)));

__device__ __forceinline__ ush f2bf(float f) {           // RNE fp32->bf16
    unsigned u = __float_as_uint(f);
    unsigned r = (u + 0x7FFFu + ((u >> 16) & 1u)) >> 16;
    return (ush)r;
}
__device__ __forceinline__ float bf2f(ush h) {
    return __uint_as_float(((unsigned)h) << 16);
}
// trunc-split 8 floats into hi bf16 (truncation) + lo bf16 (RNE of residual).
__device__ __forceinline__ void split8(float4 f0, float4 f1, uint4& h, uint4& l) {
    float f[8] = {f0.x, f0.y, f0.z, f0.w, f1.x, f1.y, f1.z, f1.w};
    unsigned hu[8], lu[8];
    #pragma unroll
    for (int j = 0; j < 8; ++j) {
        unsigned u = __float_as_uint(f[j]);
        hu[j] = u >> 16;
        float lo = f[j] - __uint_as_float(u & 0xFFFF0000u);
        lu[j] = (unsigned)f2bf(lo);
    }
    h.x = hu[0] | (hu[1] << 16); h.y = hu[2] | (hu[3] << 16);
    h.z = hu[4] | (hu[5] << 16); h.w = hu[6] | (hu[7] << 16);
    l.x = lu[0] | (lu[1] << 16); l.y = lu[2] | (lu[3] << 16);
    l.z = lu[4] | (lu[5] << 16); l.w = lu[6] | (lu[7] << 16);
}

// ws layout (float offsets), total = 10,552,320 floats = 42.2 MB.
//  A [0,2097152)        : vtg bf16 [512][8192]
//  B [2097152,4194304)  : xt bf16 -> (after time path) Mrow/Rl/pm/pl
//  C [4194304,8388608)  : weights hi/lo (dead after gemms; R8: unused late)
//  D [8388608,10485760) : qh,ql,kh,kl bf16 [8192][128]
//  E [10485760,10552320): pP,pQ,Ad,Qt fp32

// ---------------------------------------------------------------------------
// cast_w01: W0,W1 [128][512] fp32 -> W01h/W01l [256][512] bf16
// ---------------------------------------------------------------------------
__global__ __launch_bounds__(256) void cast_w01(const float* __restrict__ W0,
                                                const float* __restrict__ W1,
                                                ush* __restrict__ W01h,
                                                ush* __restrict__ W01l) {
    int idx = (blockIdx.x * 256 + threadIdx.x) * 8;      // 131072 elements total
    int r = idx >> 9, c = idx & 511;
    const float* src = (r < 128) ? &W0[r * 512 + c] : &W1[(r - 128) * 512 + c];
    float4 f0 = *(const float4*)src;
    float4 f1 = *(const float4*)(src + 4);
    uint4 h, l;
    split8(f0, f1, h, l);
    *(uint4*)&W01h[idx] = h;
    *(uint4*)&W01l[idx] = l;
}

// ---------------------------------------------------------------------------
// cast_wT: wm/wt [512k][512n] fp32 -> transposed hi/lo bf16 [512n][512k]
// ---------------------------------------------------------------------------
__global__ __launch_bounds__(256) void cast_wT(const float* __restrict__ wm,
                                               const float* __restrict__ wt,
                                               ush* __restrict__ wmTh, ush* __restrict__ wmTl,
                                               ush* __restrict__ wtTh, ush* __restrict__ wtTl) {
    const float* src = blockIdx.z ? wt : wm;
    ush* oh = blockIdx.z ? wtTh : wmTh;
    ush* ol = blockIdx.z ? wtTl : wmTl;
    __shared__ float T[64][65];
    const int t = threadIdx.x;
    const int k0 = blockIdx.y * 64, n0 = blockIdx.x * 64;
    #pragma unroll
    for (int u = 0; u < 4; ++u) {
        int idx = u * 256 + t;
        int r = idx >> 4, c4 = (idx & 15) * 4;
        *(float4*)&T[r][c4] = *(const float4*)&src[(k0 + r) * 512 + n0 + c4];
    }
    __syncthreads();
    #pragma unroll
    for (int u = 0; u < 4; ++u) {
        int idx = u * 256 + t;
        int a = idx >> 4, b4 = (idx & 15) * 4;   // out row n0+a, k cols k0+b4..+3
        unsigned hu[4], lu[4];
        #pragma unroll
        for (int j = 0; j < 4; ++j) {
            float f = T[b4 + j][a];
            unsigned uu = __float_as_uint(f);
            hu[j] = uu >> 16;
            lu[j] = (unsigned)f2bf(f - __uint_as_float(uu & 0xFFFF0000u));
        }
        uint2 hp, lp;
        hp.x = hu[0] | (hu[1] << 16); hp.y = hu[2] | (hu[3] << 16);
        lp.x = lu[0] | (lu[1] << 16); lp.y = lu[2] | (lu[3] << 16);
        *(uint2*)&oh[(n0 + a) * 512 + k0 + b4] = hp;
        *(uint2*)&ol[(n0 + a) * 512 + k0 + b4] = lp;
    }
}

// ---------------------------------------------------------------------------
// gemm_xv: C = x @ w (hi/lo bf16 MFMA, 3 terms), 128x128 tile, BK=32.
// z=0: w=weight, writes vtg TRANSPOSED (bf16). z=1: w=weight_time, writes xt.
// ---------------------------------------------------------------------------
__global__ __launch_bounds__(256) void gemm_xv(const float* __restrict__ x,
    const ush* __restrict__ wmTh, const ush* __restrict__ wmTl,
    const ush* __restrict__ wtTh, const ush* __restrict__ wtTl,
    ush* __restrict__ vtg, ush* __restrict__ xtb) {
    const bool isV = (blockIdx.z == 0);
    const ush* Bhg = isV ? wmTh : wtTh;
    const ush* Blg = isV ? wmTl : wtTl;
    __shared__ __align__(16) ush sm[20480];   // 40 KB; reused as LT in epilogue
    ush* Ah = sm;
    ush* Al = sm + 5120;
    ush* Bh = sm + 10240;
    ush* Bl = sm + 15360;
    const int t = threadIdx.x;
    const int lane = t & 63, w = t >> 6;
    const int l15 = lane & 15, g4 = lane >> 4;
    const int m0 = blockIdx.y * 128, n0 = blockIdx.x * 128;
    const int wm0 = (w & 1) * 64, wn0 = (w >> 1) * 64;
    f32x4 acc[4][4];
    #pragma unroll
    for (int mt = 0; mt < 4; ++mt)
        #pragma unroll
        for (int nt = 0; nt < 4; ++nt)
            acc[mt][nt] = (f32x4){0.f, 0.f, 0.f, 0.f};

    const int am = t >> 1, akh = (t & 1) * 16;
    for (int k0 = 0; k0 < 512; k0 += 32) {
        __syncthreads();
        {   // stage A (x fp32 -> hi/lo bf16 granules)
            const float* src = &x[(m0 + am) * 512 + k0 + akh];
            float4 f0 = *(const float4*)&src[0];
            float4 f1 = *(const float4*)&src[4];
            float4 f2 = *(const float4*)&src[8];
            float4 f3 = *(const float4*)&src[12];
            uint4 h0, l0, h1, l1;
            split8(f0, f1, h0, l0);
            split8(f2, f3, h1, l1);
            int s0 = am * 5 + (akh >> 3);
            *(uint4*)&Ah[s0 * 8] = h0; *(uint4*)&Ah[(s0 + 1) * 8] = h1;
            *(uint4*)&Al[s0 * 8] = l0; *(uint4*)&Al[(s0 + 1) * 8] = l1;
        }
        #pragma unroll
        for (int u = 0; u < 2; ++u) {   // stage B (pre-split bf16)
            int s = u * 256 + t;
            int n = s >> 2, g = s & 3;
            int srco = (n0 + n) * 512 + k0 + g * 8;
            int slot = n * 5 + g;
            *(uint4*)&Bh[slot * 8] = *(const uint4*)&Bhg[srco];
            *(uint4*)&Bl[slot * 8] = *(const uint4*)&Blg[srco];
        }
        __syncthreads();
        bf16x8 ah[4], al[4], bh[4], bl[4];
        #pragma unroll
        for (int mt = 0; mt < 4; ++mt) {
            int slot = (wm0 + mt * 16 + l15) * 5 + g4;
            ah[mt] = *(const bf16x8*)&Ah[slot * 8];
            al[mt] = *(const bf16x8*)&Al[slot * 8];
        }
        #pragma unroll
        for (int nt = 0; nt < 4; ++nt) {
            int slot = (wn0 + nt * 16 + l15) * 5 + g4;
            bh[nt] = *(const bf16x8*)&Bh[slot * 8];
            bl[nt] = *(const bf16x8*)&Bl[slot * 8];
        }
        #pragma unroll
        for (int mt = 0; mt < 4; ++mt)
            #pragma unroll
            for (int nt = 0; nt < 4; ++nt) {
                acc[mt][nt] = __builtin_amdgcn_mfma_f32_16x16x32_bf16(ah[mt], bh[nt], acc[mt][nt], 0, 0, 0);
                acc[mt][nt] = __builtin_amdgcn_mfma_f32_16x16x32_bf16(al[mt], bh[nt], acc[mt][nt], 0, 0, 0);
                acc[mt][nt] = __builtin_amdgcn_mfma_f32_16x16x32_bf16(ah[mt], bl[nt], acc[mt][nt], 0, 0, 0);
            }
    }

    if (!isV) {   // xt: direct bf16 stores
        #pragma unroll
        for (int mt = 0; mt < 4; ++mt)
            #pragma unroll
            for (int nt = 0; nt < 4; ++nt) {
                int col = n0 + wn0 + nt * 16 + l15;
                int rowb = m0 + wm0 + mt * 16 + g4 * 4;
                #pragma unroll
                for (int reg = 0; reg < 4; ++reg)
                    xtb[(rowb + reg) * 512 + col] = f2bf(acc[mt][nt][reg]);
            }
    } else {      // vtg: transpose through LDS
        __syncthreads();
        #pragma unroll
        for (int mt = 0; mt < 4; ++mt)
            #pragma unroll
            for (int nt = 0; nt < 4; ++nt) {
                int nl = wn0 + nt * 16 + l15;
                int mb = wm0 + mt * 16 + g4 * 4;
                uint2 pk;
                pk.x = (unsigned)f2bf(acc[mt][nt][0]) | ((unsigned)f2bf(acc[mt][nt][1]) << 16);
                pk.y = (unsigned)f2bf(acc[mt][nt][2]) | ((unsigned)f2bf(acc[mt][nt][3]) << 16);
                *(uint2*)&sm[nl * 136 + mb] = pk;
            }
        __syncthreads();
        int a = t >> 1, off = (t & 1) * 64;
        #pragma unroll
        for (int u = 0; u < 8; ++u)
            *(uint4*)&vtg[(n0 + a) * 8192 + m0 + off + u * 8] =
                *(const uint4*)&sm[a * 136 + off + u * 8];
    }
}

// ---------------------------------------------------------------------------
// gemm_qk: [q|k] = x @ [W0|W1]^T (hi/lo MFMA) -> qh/ql/kh/kl
// BM=64, BN=128 -> grid (2,128) = 256 blocks.
// ---------------------------------------------------------------------------
__global__ __launch_bounds__(256) void gemm_qk(const float* __restrict__ x,
    const ush* __restrict__ W01h, const ush* __restrict__ W01l,
    ush* __restrict__ qh, ush* __restrict__ ql,
    ush* __restrict__ kh, ush* __restrict__ kl) {
    __shared__ __align__(16) ush sm[15360];   // Ah 2560 | Al 2560 | Bh 5120 | Bl 5120
    ush* Ah = sm;
    ush* Al = sm + 2560;
    ush* Bh = sm + 5120;
    ush* Bl = sm + 10240;
    const int t = threadIdx.x;
    const int lane = t & 63, w = t >> 6;
    const int l15 = lane & 15, g4 = lane >> 4;
    const int m0 = blockIdx.y * 64, n0 = blockIdx.x * 128;
    const int wm0 = (w & 1) * 32, wn0 = (w >> 1) * 64;
    f32x4 acc[2][4];
    #pragma unroll
    for (int mt = 0; mt < 2; ++mt)
        #pragma unroll
        for (int nt = 0; nt < 4; ++nt)
            acc[mt][nt] = (f32x4){0.f, 0.f, 0.f, 0.f};

    const int ar = t >> 2, ag = t & 3;       // A: row ar, k-granule ag
    for (int k0 = 0; k0 < 512; k0 += 32) {
        __syncthreads();
        {   // stage A (64 rows x 32 k, split on the fly)
            const float* src = &x[(m0 + ar) * 512 + k0 + ag * 8];
            float4 f0 = *(const float4*)&src[0];
            float4 f1 = *(const float4*)&src[4];
            uint4 h, l;
            split8(f0, f1, h, l);
            int slot = ar * 5 + ag;
            *(uint4*)&Ah[slot * 8] = h;
            *(uint4*)&Al[slot * 8] = l;
        }
        #pragma unroll
        for (int u = 0; u < 2; ++u) {        // stage B (128 n x 32 k, pre-split)
            int s = u * 256 + t;
            int n = s >> 2, g = s & 3;
            int srco = (n0 + n) * 512 + k0 + g * 8;
            int slot = n * 5 + g;
            *(uint4*)&Bh[slot * 8] = *(const uint4*)&W01h[srco];
            *(uint4*)&Bl[slot * 8] = *(const uint4*)&W01l[srco];
        }
        __syncthreads();
        bf16x8 ah[2], al[2], bh[4], bl[4];
        #pragma unroll
        for (int mt = 0; mt < 2; ++mt) {
            int slot = (wm0 + mt * 16 + l15) * 5 + g4;
            ah[mt] = *(const bf16x8*)&Ah[slot * 8];
            al[mt] = *(const bf16x8*)&Al[slot * 8];
        }
        #pragma unroll
        for (int nt = 0; nt < 4; ++nt) {
            int slot = (wn0 + nt * 16 + l15) * 5 + g4;
            bh[nt] = *(const bf16x8*)&Bh[slot * 8];
            bl[nt] = *(const bf16x8*)&Bl[slot * 8];
        }
        #pragma unroll
        for (int mt = 0; mt < 2; ++mt)
            #pragma unroll
            for (int nt = 0; nt < 4; ++nt) {
                acc[mt][nt] = __builtin_amdgcn_mfma_f32_16x16x32_bf16(ah[mt], bh[nt], acc[mt][nt], 0, 0, 0);
                acc[mt][nt] = __builtin_amdgcn_mfma_f32_16x16x32_bf16(al[mt], bh[nt], acc[mt][nt], 0, 0, 0);
                acc[mt][nt] = __builtin_amdgcn_mfma_f32_16x16x32_bf16(ah[mt], bl[nt], acc[mt][nt], 0, 0, 0);
            }
    }
    ush* oh = (n0 == 0) ? qh : kh;
    ush* ol = (n0 == 0) ? ql : kl;
    #pragma unroll
    for (int mt = 0; mt < 2; ++mt)
        #pragma unroll
        for (int nt = 0; nt < 4; ++nt) {
            int col = wn0 + nt * 16 + l15;
            int rowb = m0 + wm0 + mt * 16 + g4 * 4;
            #pragma unroll
            for (int reg = 0; reg < 4; ++reg) {
                float v = acc[mt][nt][reg];
                unsigned u = __float_as_uint(v);
                ush h = (ush)(u >> 16);
                ush lo = f2bf(v - __uint_as_float(u & 0xFFFF0000u));
                oh[(rowb + reg) * 128 + col] = h;
                ol[(rowb + reg) * 128 + col] = lo;
            }
        }
}

// ---------------------------------------------------------------------------
// time path (xt bf16)
// ---------------------------------------------------------------------------
__global__ __launch_bounds__(256) void time_part1(const ush* __restrict__ xtb,
                                                  float* __restrict__ pP,
                                                  float* __restrict__ pQ) {
    int d = blockIdx.x * 256 + threadIdx.x;
    int r0 = blockIdx.y * 128;
    float sp = 0.f, sq = 0.f;
    for (int r = 0; r < 128; ++r) {
        float v = bf2f(xtb[(r0 + r) * 512 + d]);
        sp += v;
        sq += (float)(r0 + r) * v;
    }
    pP[blockIdx.y * 512 + d] = sp;
    pQ[blockIdx.y * 512 + d] = sq;
}

__global__ __launch_bounds__(512) void time_part2(float* __restrict__ pP,
                                                  float* __restrict__ pQ,
                                                  float* __restrict__ Ad,
                                                  float* __restrict__ Qt) {
    int d = threadIdx.x;
    float rp = 0.f, rq = 0.f;
    for (int c = 0; c < 64; ++c) {
        int idx = c * 512 + d;
        float p = pP[idx], qv = pQ[idx];
        pP[idx] = rp; pQ[idx] = rq;
        rp += p; rq += qv;
    }
    Ad[d] = rp; Qt[d] = rq;
}

__global__ __launch_bounds__(256) void time_part3(const ush* __restrict__ xtb,
                                                  const float* __restrict__ pP,
                                                  const float* __restrict__ pQ,
                                                  const float* __restrict__ Ad,
                                                  const float* __restrict__ Qt,
                                                  float* __restrict__ out) {
    int d = blockIdx.x * 256 + threadIdx.x;
    int r0 = blockIdx.y * 128;
    float P = pP[blockIdx.y * 512 + d];
    float Q = pQ[blockIdx.y * 512 + d];
    float A = Ad[d], Qtot = Qt[d];
    for (int r = 0; r < 128; ++r) {
        int i = r0 + r;
        float v = bf2f(xtb[i * 512 + d]);
        P += v;
        float fi = (float)i;
        Q += fi * v;
        float B = 2.f * fi * P - 2.f * Q + Qtot - fi * A;
        int Si = 67108864 - (i * (i + 1)) / 2 - ((8191 - i) * (8192 - i)) / 2;
        float T = (8192.f * A - B) / (float)Si;
        out[i * 512 + d] = 0.5f * T;
    }
}

// ---------------------------------------------------------------------------
// pass1: softmax stats, j-split x8. grid (8 jchunks, 256 iblocks).
// Per-lane (m,l) running stats; one butterfly merge at end.
// ---------------------------------------------------------------------------
__global__ __launch_bounds__(256) void pass1(const ush* __restrict__ qhg,
                                             const ush* __restrict__ qlg,
                                             const ush* __restrict__ khg,
                                             const ush* __restrict__ klg,
                                             float* __restrict__ pm,
                                             float* __restrict__ pl) {
    __shared__ __align__(16) ush Kh[32 * 128];
    __shared__ __align__(16) ush Kl[32 * 128];
    __shared__ float sm_[2][32], sl_[2][32];
    const int t = threadIdx.x;
    const int lane = t & 63, w = t >> 6;
    const int rt = w & 1, ct = w >> 1;
    const int i0 = blockIdx.y * 32;
    const int jbase = blockIdx.x * 1024;
    const int l15 = lane & 15, g = lane >> 4;

    bf16x8 Qh[4], Ql[4];
    {
        int qrow = i0 + rt * 16 + l15;
        #pragma unroll
        for (int kt = 0; kt < 4; ++kt) {
            Qh[kt] = *(const bf16x8*)&qhg[qrow * 128 + kt * 32 + g * 8];
            Ql[kt] = *(const bf16x8*)&qlg[qrow * 128 + kt * 32 + g * 8];
        }
    }
    float m_run[4] = {-INFINITY, -INFINITY, -INFINITY, -INFINITY};
    float l_run[4] = {0.f, 0.f, 0.f, 0.f};

    for (int jt = 0; jt < 32; ++jt) {
        int j0 = jbase + jt * 32;
        __syncthreads();
        #pragma unroll
        for (int u = 0; u < 2; ++u) {
            int s = u * 256 + t;
            int n = s >> 4, gl = (s & 15) ^ (n & 15);
            int src = (j0 + n) * 128 + gl * 8;
            *(uint4*)&Kh[s * 8] = *(const uint4*)&khg[src];
            *(uint4*)&Kl[s * 8] = *(const uint4*)&klg[src];
        }
        __syncthreads();

        bf16x8 kbh[4], kbl[4];
        {
            int n = ct * 16 + l15;
            #pragma unroll
            for (int kt = 0; kt < 4; ++kt) {
                int slot = n * 16 + ((kt * 4 + g) ^ (n & 15));
                kbh[kt] = *(const bf16x8*)&Kh[slot * 8];
                kbl[kt] = *(const bf16x8*)&Kl[slot * 8];
            }
        }
        f32x4 s4 = {0.f, 0.f, 0.f, 0.f};
        #pragma unroll
        for (int kt = 0; kt < 4; ++kt) s4 = __builtin_amdgcn_mfma_f32_16x16x32_bf16(Qh[kt], kbh[kt], s4, 0, 0, 0);
        #pragma unroll
        for (int kt = 0; kt < 4; ++kt) s4 = __builtin_amdgcn_mfma_f32_16x16x32_bf16(Ql[kt], kbh[kt], s4, 0, 0, 0);
        #pragma unroll
        for (int kt = 0; kt < 4; ++kt) s4 = __builtin_amdgcn_mfma_f32_16x16x32_bf16(Qh[kt], kbl[kt], s4, 0, 0, 0);

        #pragma unroll
        for (int reg = 0; reg < 4; ++reg) {    // per-lane online (m,l) only
            float s = s4[reg];
            float mn = fmaxf(m_run[reg], s);
            l_run[reg] = l_run[reg] * __expf(m_run[reg] - mn) + __expf(s - mn);
            m_run[reg] = mn;
        }
    }
    // butterfly merge over the 16 col-lanes
    #pragma unroll
    for (int st = 1; st < 16; st <<= 1) {
        #pragma unroll
        for (int reg = 0; reg < 4; ++reg) {
            float mo = __shfl_xor(m_run[reg], st);
            float lo = __shfl_xor(l_run[reg], st);
            float mn = fmaxf(m_run[reg], mo);
            l_run[reg] = l_run[reg] * __expf(m_run[reg] - mn) + lo * __expf(mo - mn);
            m_run[reg] = mn;
        }
    }
    if (l15 == 0) {
        #pragma unroll
        for (int reg = 0; reg < 4; ++reg) {
            sm_[ct][rt * 16 + g * 4 + reg] = m_run[reg];
            sl_[ct][rt * 16 + g * 4 + reg] = l_run[reg];
        }
    }
    __syncthreads();
    if (t < 32) {
        float M = fmaxf(sm_[0][t], sm_[1][t]);
        float l = sl_[0][t] * __expf(sm_[0][t] - M) + sl_[1][t] * __expf(sm_[1][t] - M);
        pm[blockIdx.x * 8192 + i0 + t] = M;
        pl[blockIdx.x * 8192 + i0 + t] = l;
    }
}

__global__ __launch_bounds__(256) void merge_stats(const float* __restrict__ pm,
                                                   const float* __restrict__ pl,
                                                   float* __restrict__ Mrow,
                                                   float* __restrict__ Rl) {
    int i = blockIdx.x * 256 + threadIdx.x;
    float M = pm[i];
    #pragma unroll
    for (int js = 1; js < 8; ++js) M = fmaxf(M, pm[js * 8192 + i]);
    float l = 0.f;
    #pragma unroll
    for (int js = 0; js < 8; ++js) l += pl[js * 8192 + i] * __expf(pm[js * 8192 + i] - M);
    Mrow[i] = M;
    Rl[i] = 1.0f / l;
}

// ---------------------------------------------------------------------------
// pass2: out += 0.5 * exp(S-M)/l @ V, transposed PV.
// R8: BM=64 (R4's work ratio: 56 MFMA/wave per 48KB staged — R7's BM=32
// halved compute per staging and regressed), j-split 4 => grid (4,128) = 512
// blocks = 2 blocks/CU co-resident (R7 proved the dispatcher delivers 2/CU at
// grid 512; VGPR 156 & LDS 53KB both fit 2). Epilogue: fp32 atomicAdd of
// 0.5*O directly into out (time_part3 pre-initializes out on this stream) —
// removes the 4-partial buffer need and merge_k entirely.
// ---------------------------------------------------------------------------
__global__ __launch_bounds__(256, 2) void pass2(const ush* __restrict__ qhg,
                                                const ush* __restrict__ qlg,
                                                const ush* __restrict__ khg,
                                                const ush* __restrict__ klg,
                                                const ush* __restrict__ vtg,
                                                const float* __restrict__ Mrow,
                                                const float* __restrict__ Rl,
                                                float* __restrict__ out) {
    __shared__ __align__(16) ush Kh[32 * 128];   // 8 KB
    __shared__ __align__(16) ush Kl[32 * 128];   // 8 KB
    __shared__ __align__(16) ush Vt[512 * 32];   // 32 KB
    __shared__ __align__(16) ush P[64 * 40];     // 5 KB

    const int t = threadIdx.x;
    const int lane = t & 63, w = t >> 6;
    const int l15 = lane & 15, g = lane >> 4;
    const int i0 = blockIdx.y * 64;
    const int jbase = blockIdx.x * 2048;         // j-quarter

    bf16x8 Qh[2][4], Ql[2][4];
    #pragma unroll
    for (int rt = 0; rt < 2; ++rt) {
        int qrow = i0 + 32 * (w & 1) + rt * 16 + l15;
        #pragma unroll
        for (int kt = 0; kt < 4; ++kt) {
            Qh[rt][kt] = *(const bf16x8*)&qhg[qrow * 128 + kt * 32 + g * 8];
            Ql[rt][kt] = *(const bf16x8*)&qlg[qrow * 128 + kt * 32 + g * 8];
        }
    }
    float Mv[2][4], Rv[2][4];
    #pragma unroll
    for (int rt = 0; rt < 2; ++rt)
        #pragma unroll
        for (int reg = 0; reg < 4; ++reg) {
            int row = i0 + 32 * (w & 1) + rt * 16 + g * 4 + reg;
            Mv[rt][reg] = Mrow[row];
            Rv[rt][reg] = Rl[row];
        }

    f32x4 acc[8][4];
    #pragma unroll
    for (int mt = 0; mt < 8; ++mt)
        #pragma unroll
        for (int nt = 0; nt < 4; ++nt)
            acc[mt][nt] = (f32x4){0.f, 0.f, 0.f, 0.f};

    for (int jt = 0; jt < 64; ++jt) {
        const int j0 = jbase + jt * 32;
        __syncthreads();
        #pragma unroll
        for (int u = 0; u < 2; ++u) {          // stage K hi/lo
            int s = u * 256 + t;
            int n = s >> 4, gl = (s & 15) ^ (n & 15);
            int src = (j0 + n) * 128 + gl * 8;
            *(uint4*)&Kh[s * 8] = *(const uint4*)&khg[src];
            *(uint4*)&Kl[s * 8] = *(const uint4*)&klg[src];
        }
        #pragma unroll
        for (int u = 0; u < 8; ++u) {          // stage Vt (cols j0..j0+31)
            int s = u * 256 + t;
            int c = s >> 2, gl = (s & 3) ^ ((c >> 1) & 3);
            *(uint4*)&Vt[s * 8] = *(const uint4*)&vtg[c * 8192 + j0 + gl * 8];
        }
        __syncthreads();

        // ---- S = Q K^T ----
        bf16x8 kbh[4], kbl[4];
        {
            int n = (w >> 1) * 16 + l15;
            #pragma unroll
            for (int kt = 0; kt < 4; ++kt) {
                int slot = n * 16 + ((kt * 4 + g) ^ (n & 15));
                kbh[kt] = *(const bf16x8*)&Kh[slot * 8];
                kbl[kt] = *(const bf16x8*)&Kl[slot * 8];
            }
        }
        #pragma unroll
        for (int rt = 0; rt < 2; ++rt) {
            f32x4 s4 = {0.f, 0.f, 0.f, 0.f};
            #pragma unroll
            for (int kt = 0; kt < 4; ++kt) s4 = __builtin_amdgcn_mfma_f32_16x16x32_bf16(Qh[rt][kt], kbh[kt], s4, 0, 0, 0);
            #pragma unroll
            for (int kt = 0; kt < 4; ++kt) s4 = __builtin_amdgcn_mfma_f32_16x16x32_bf16(Ql[rt][kt], kbh[kt], s4, 0, 0, 0);
            #pragma unroll
            for (int kt = 0; kt < 4; ++kt) s4 = __builtin_amdgcn_mfma_f32_16x16x32_bf16(Qh[rt][kt], kbl[kt], s4, 0, 0, 0);
            #pragma unroll
            for (int reg = 0; reg < 4; ++reg) {
                float p = __expf(s4[reg] - Mv[rt][reg]) * Rv[rt][reg];
                int row = 32 * (w & 1) + rt * 16 + g * 4 + reg;
                int col = (w >> 1) * 16 + l15;
                P[row * 40 + col] = f2bf(p);
            }
        }
        __syncthreads();                       // P visible

        // ---- O^T += Vt_tile * P^T ----
        bf16x8 Pb[4];
        #pragma unroll
        for (int nt = 0; nt < 4; ++nt)
            Pb[nt] = *(const bf16x8*)&P[(nt * 16 + l15) * 40 + g * 8];
        #pragma unroll
        for (int mt = 0; mt < 8; ++mt) {
            int c = w * 128 + mt * 16 + l15;
            int slot = c * 4 + (g ^ ((c >> 1) & 3));
            bf16x8 vf = *(const bf16x8*)&Vt[slot * 8];
            #pragma unroll
            for (int nt = 0; nt < 4; ++nt)
                acc[mt][nt] = __builtin_amdgcn_mfma_f32_16x16x32_bf16(vf, Pb[nt], acc[mt][nt], 0, 0, 0);
        }
    }

    // epilogue: atomic accumulate 0.5*O into out (4 j-quarters per element)
    #pragma unroll
    for (int mt = 0; mt < 8; ++mt)
        #pragma unroll
        for (int nt = 0; nt < 4; ++nt) {
            int qrow = i0 + nt * 16 + l15;
            int vcol = w * 128 + mt * 16 + g * 4;
            float* dst = &out[qrow * 512 + vcol];
            #pragma unroll
            for (int reg = 0; reg < 4; ++reg)
                atomicAdd(dst + reg, 0.5f * acc[mt][nt][reg]);
        }
}

// ---------------------------------------------------------------------------
extern "C" void kernel_launch(void* const* d_in, const int* in_sizes, int n_in,
                              void* d_out, int out_size, void* d_ws, size_t ws_size,
                              hipStream_t stream) {
    const float* x  = (const float*)d_in[0];
    const float* W0 = (const float*)d_in[1];
    const float* W1 = (const float*)d_in[2];
    const float* wm = (const float*)d_in[3];
    const float* wt = (const float*)d_in[4];
    float* out = (float*)d_out;
    float* ws  = (float*)d_ws;

    // Region A
    ush* vtg = (ush*)(ws + 0);
    // Region B: xt bf16, then stats overlay after time path
    ush* xtb  = (ush*)(ws + 2097152);
    float* Mr = ws + 2097152;
    float* Rl = ws + 2105344;
    float* pm = ws + 2113536;
    float* pl = ws + 2179072;
    // Region C: weights (dead after the gemms)
    ush* W01h = (ush*)(ws + 4194304);
    ush* W01l = (ush*)(ws + 4259840);
    ush* wmTh = (ush*)(ws + 4325376);
    ush* wmTl = (ush*)(ws + 4456448);
    ush* wtTh = (ush*)(ws + 4587520);
    ush* wtTl = (ush*)(ws + 4718592);
    // Region D
    ush* qh = (ush*)(ws + 8388608);
    ush* ql = (ush*)(ws + 8912896);
    ush* kh = (ush*)(ws + 9437184);
    ush* kl = (ush*)(ws + 9961472);
    // Region E
    float* pP = ws + 10485760;
    float* pQ = ws + 10518528;
    float* Ad = ws + 10551296;
    float* Qt = ws + 10551808;

    cast_w01   <<<dim3(64),       256, 0, stream>>>(W0, W1, W01h, W01l);
    cast_wT    <<<dim3(8, 8, 2),  256, 0, stream>>>(wm, wt, wmTh, wmTl, wtTh, wtTl);
    gemm_xv    <<<dim3(4, 64, 2), 256, 0, stream>>>(x, wmTh, wmTl, wtTh, wtTl, vtg, xtb);
    gemm_qk    <<<dim3(2, 128),   256, 0, stream>>>(x, W01h, W01l, qh, ql, kh, kl);
    time_part1 <<<dim3(2, 64),    256, 0, stream>>>(xtb, pP, pQ);
    time_part2 <<<dim3(1),        512, 0, stream>>>(pP, pQ, Ad, Qt);
    time_part3 <<<dim3(2, 64),    256, 0, stream>>>(xtb, pP, pQ, Ad, Qt, out);
    pass1      <<<dim3(8, 256),   256, 0, stream>>>(qh, ql, kh, kl, pm, pl);
    merge_stats<<<dim3(32),       256, 0, stream>>>(pm, pl, Mr, Rl);
    pass2      <<<dim3(4, 128),   256, 0, stream>>>(qh, ql, kh, kl, vtg, Mr, Rl, out);
}

// Round 9
// 429.259 us; speedup vs baseline: 1.5490x; 1.5490x over previous
//
#include <hip/hip_runtime.h>
#include <math.h>

// Problem constants
#define NN 8192
#define INS 512
#define FEAT 128

typedef unsigned short ush;
typedef short bf16x8 __attribute__((ext_vector_type(8)));
typedef float f32x4 __attribute__((ext_vector_type(4)));

__device__ __forceinline__ ush f2bf(float f) {           // RNE fp32->bf16
    unsigned u = __float_as_uint(f);
    unsigned r = (u + 0x7FFFu + ((u >> 16) & 1u)) >> 16;
    return (ush)r;
}
__device__ __forceinline__ float bf2f(ush h) {
    return __uint_as_float(((unsigned)h) << 16);
}
// async 16B global -> LDS (gfx950 global_load_lds_dwordx4). LDS dst must be
// wave-uniform-base + lane*16 — our staging layouts satisfy this by design.
__device__ __forceinline__ void cp16(const ush* g, ush* l) {
    __builtin_amdgcn_global_load_lds(
        (const __attribute__((address_space(1))) void*)g,
        (__attribute__((address_space(3))) void*)l, 16, 0, 0);
}
// trunc-split 8 floats into hi bf16 (truncation) + lo bf16 (RNE of residual).
__device__ __forceinline__ void split8(float4 f0, float4 f1, uint4& h, uint4& l) {
    float f[8] = {f0.x, f0.y, f0.z, f0.w, f1.x, f1.y, f1.z, f1.w};
    unsigned hu[8], lu[8];
    #pragma unroll
    for (int j = 0; j < 8; ++j) {
        unsigned u = __float_as_uint(f[j]);
        hu[j] = u >> 16;
        float lo = f[j] - __uint_as_float(u & 0xFFFF0000u);
        lu[j] = (unsigned)f2bf(lo);
    }
    h.x = hu[0] | (hu[1] << 16); h.y = hu[2] | (hu[3] << 16);
    h.z = hu[4] | (hu[5] << 16); h.w = hu[6] | (hu[7] << 16);
    l.x = lu[0] | (lu[1] << 16); l.y = lu[2] | (lu[3] << 16);
    l.z = lu[4] | (lu[5] << 16); l.w = lu[6] | (lu[7] << 16);
}

// ws layout (float offsets), total = 10,552,320 floats = 42.2 MB.
//  A [0,2097152)        : vtg bf16 [512][8192]
//  B [2097152,4194304)  : xt bf16 -> (after time path) Mrow/Rl/pm/pl
//  C [4194304,8388608)  : weights hi/lo (early) -> part0/part1 bf16 (pass2)
//  D [8388608,10485760) : qh,ql,kh,kl bf16 [8192][128]
//  E [10485760,10552320): pP,pQ,Ad,Qt fp32

// ---------------------------------------------------------------------------
// cast_w01: W0,W1 [128][512] fp32 -> W01h/W01l [256][512] bf16
// ---------------------------------------------------------------------------
__global__ __launch_bounds__(256) void cast_w01(const float* __restrict__ W0,
                                                const float* __restrict__ W1,
                                                ush* __restrict__ W01h,
                                                ush* __restrict__ W01l) {
    int idx = (blockIdx.x * 256 + threadIdx.x) * 8;      // 131072 elements total
    int r = idx >> 9, c = idx & 511;
    const float* src = (r < 128) ? &W0[r * 512 + c] : &W1[(r - 128) * 512 + c];
    float4 f0 = *(const float4*)src;
    float4 f1 = *(const float4*)(src + 4);
    uint4 h, l;
    split8(f0, f1, h, l);
    *(uint4*)&W01h[idx] = h;
    *(uint4*)&W01l[idx] = l;
}

// ---------------------------------------------------------------------------
// cast_wT: wm/wt [512k][512n] fp32 -> transposed hi/lo bf16 [512n][512k]
// ---------------------------------------------------------------------------
__global__ __launch_bounds__(256) void cast_wT(const float* __restrict__ wm,
                                               const float* __restrict__ wt,
                                               ush* __restrict__ wmTh, ush* __restrict__ wmTl,
                                               ush* __restrict__ wtTh, ush* __restrict__ wtTl) {
    const float* src = blockIdx.z ? wt : wm;
    ush* oh = blockIdx.z ? wtTh : wmTh;
    ush* ol = blockIdx.z ? wtTl : wmTl;
    __shared__ float T[64][65];
    const int t = threadIdx.x;
    const int k0 = blockIdx.y * 64, n0 = blockIdx.x * 64;
    #pragma unroll
    for (int u = 0; u < 4; ++u) {
        int idx = u * 256 + t;
        int r = idx >> 4, c4 = (idx & 15) * 4;
        *(float4*)&T[r][c4] = *(const float4*)&src[(k0 + r) * 512 + n0 + c4];
    }
    __syncthreads();
    #pragma unroll
    for (int u = 0; u < 4; ++u) {
        int idx = u * 256 + t;
        int a = idx >> 4, b4 = (idx & 15) * 4;   // out row n0+a, k cols k0+b4..+3
        unsigned hu[4], lu[4];
        #pragma unroll
        for (int j = 0; j < 4; ++j) {
            float f = T[b4 + j][a];
            unsigned uu = __float_as_uint(f);
            hu[j] = uu >> 16;
            lu[j] = (unsigned)f2bf(f - __uint_as_float(uu & 0xFFFF0000u));
        }
        uint2 hp, lp;
        hp.x = hu[0] | (hu[1] << 16); hp.y = hu[2] | (hu[3] << 16);
        lp.x = lu[0] | (lu[1] << 16); lp.y = lu[2] | (lu[3] << 16);
        *(uint2*)&oh[(n0 + a) * 512 + k0 + b4] = hp;
        *(uint2*)&ol[(n0 + a) * 512 + k0 + b4] = lp;
    }
}

// ---------------------------------------------------------------------------
// gemm_xv: C = x @ w (hi/lo bf16 MFMA, 3 terms), 128x128 tile, BK=32.
// z=0: w=weight, writes vtg TRANSPOSED (bf16). z=1: w=weight_time, writes xt.
// ---------------------------------------------------------------------------
__global__ __launch_bounds__(256) void gemm_xv(const float* __restrict__ x,
    const ush* __restrict__ wmTh, const ush* __restrict__ wmTl,
    const ush* __restrict__ wtTh, const ush* __restrict__ wtTl,
    ush* __restrict__ vtg, ush* __restrict__ xtb) {
    const bool isV = (blockIdx.z == 0);
    const ush* Bhg = isV ? wmTh : wtTh;
    const ush* Blg = isV ? wmTl : wtTl;
    __shared__ __align__(16) ush sm[20480];   // 40 KB; reused as LT in epilogue
    ush* Ah = sm;
    ush* Al = sm + 5120;
    ush* Bh = sm + 10240;
    ush* Bl = sm + 15360;
    const int t = threadIdx.x;
    const int lane = t & 63, w = t >> 6;
    const int l15 = lane & 15, g4 = lane >> 4;
    const int m0 = blockIdx.y * 128, n0 = blockIdx.x * 128;
    const int wm0 = (w & 1) * 64, wn0 = (w >> 1) * 64;
    f32x4 acc[4][4];
    #pragma unroll
    for (int mt = 0; mt < 4; ++mt)
        #pragma unroll
        for (int nt = 0; nt < 4; ++nt)
            acc[mt][nt] = (f32x4){0.f, 0.f, 0.f, 0.f};

    const int am = t >> 1, akh = (t & 1) * 16;
    for (int k0 = 0; k0 < 512; k0 += 32) {
        __syncthreads();
        {   // stage A (x fp32 -> hi/lo bf16 granules)
            const float* src = &x[(m0 + am) * 512 + k0 + akh];
            float4 f0 = *(const float4*)&src[0];
            float4 f1 = *(const float4*)&src[4];
            float4 f2 = *(const float4*)&src[8];
            float4 f3 = *(const float4*)&src[12];
            uint4 h0, l0, h1, l1;
            split8(f0, f1, h0, l0);
            split8(f2, f3, h1, l1);
            int s0 = am * 5 + (akh >> 3);
            *(uint4*)&Ah[s0 * 8] = h0; *(uint4*)&Ah[(s0 + 1) * 8] = h1;
            *(uint4*)&Al[s0 * 8] = l0; *(uint4*)&Al[(s0 + 1) * 8] = l1;
        }
        #pragma unroll
        for (int u = 0; u < 2; ++u) {   // stage B (pre-split bf16)
            int s = u * 256 + t;
            int n = s >> 2, g = s & 3;
            int srco = (n0 + n) * 512 + k0 + g * 8;
            int slot = n * 5 + g;
            *(uint4*)&Bh[slot * 8] = *(const uint4*)&Bhg[srco];
            *(uint4*)&Bl[slot * 8] = *(const uint4*)&Blg[srco];
        }
        __syncthreads();
        bf16x8 ah[4], al[4], bh[4], bl[4];
        #pragma unroll
        for (int mt = 0; mt < 4; ++mt) {
            int slot = (wm0 + mt * 16 + l15) * 5 + g4;
            ah[mt] = *(const bf16x8*)&Ah[slot * 8];
            al[mt] = *(const bf16x8*)&Al[slot * 8];
        }
        #pragma unroll
        for (int nt = 0; nt < 4; ++nt) {
            int slot = (wn0 + nt * 16 + l15) * 5 + g4;
            bh[nt] = *(const bf16x8*)&Bh[slot * 8];
            bl[nt] = *(const bf16x8*)&Bl[slot * 8];
        }
        #pragma unroll
        for (int mt = 0; mt < 4; ++mt)
            #pragma unroll
            for (int nt = 0; nt < 4; ++nt) {
                acc[mt][nt] = __builtin_amdgcn_mfma_f32_16x16x32_bf16(ah[mt], bh[nt], acc[mt][nt], 0, 0, 0);
                acc[mt][nt] = __builtin_amdgcn_mfma_f32_16x16x32_bf16(al[mt], bh[nt], acc[mt][nt], 0, 0, 0);
                acc[mt][nt] = __builtin_amdgcn_mfma_f32_16x16x32_bf16(ah[mt], bl[nt], acc[mt][nt], 0, 0, 0);
            }
    }

    if (!isV) {   // xt: direct bf16 stores
        #pragma unroll
        for (int mt = 0; mt < 4; ++mt)
            #pragma unroll
            for (int nt = 0; nt < 4; ++nt) {
                int col = n0 + wn0 + nt * 16 + l15;
                int rowb = m0 + wm0 + mt * 16 + g4 * 4;
                #pragma unroll
                for (int reg = 0; reg < 4; ++reg)
                    xtb[(rowb + reg) * 512 + col] = f2bf(acc[mt][nt][reg]);
            }
    } else {      // vtg: transpose through LDS
        __syncthreads();
        #pragma unroll
        for (int mt = 0; mt < 4; ++mt)
            #pragma unroll
            for (int nt = 0; nt < 4; ++nt) {
                int nl = wn0 + nt * 16 + l15;
                int mb = wm0 + mt * 16 + g4 * 4;
                uint2 pk;
                pk.x = (unsigned)f2bf(acc[mt][nt][0]) | ((unsigned)f2bf(acc[mt][nt][1]) << 16);
                pk.y = (unsigned)f2bf(acc[mt][nt][2]) | ((unsigned)f2bf(acc[mt][nt][3]) << 16);
                *(uint2*)&sm[nl * 136 + mb] = pk;
            }
        __syncthreads();
        int a = t >> 1, off = (t & 1) * 64;
        #pragma unroll
        for (int u = 0; u < 8; ++u)
            *(uint4*)&vtg[(n0 + a) * 8192 + m0 + off + u * 8] =
                *(const uint4*)&sm[a * 136 + off + u * 8];
    }
}

// ---------------------------------------------------------------------------
// gemm_qk: [q|k] = x @ [W0|W1]^T (hi/lo MFMA) -> qh/ql/kh/kl
// BM=64, BN=128 -> grid (2,128) = 256 blocks.
// ---------------------------------------------------------------------------
__global__ __launch_bounds__(256) void gemm_qk(const float* __restrict__ x,
    const ush* __restrict__ W01h, const ush* __restrict__ W01l,
    ush* __restrict__ qh, ush* __restrict__ ql,
    ush* __restrict__ kh, ush* __restrict__ kl) {
    __shared__ __align__(16) ush sm[15360];   // Ah 2560 | Al 2560 | Bh 5120 | Bl 5120
    ush* Ah = sm;
    ush* Al = sm + 2560;
    ush* Bh = sm + 5120;
    ush* Bl = sm + 10240;
    const int t = threadIdx.x;
    const int lane = t & 63, w = t >> 6;
    const int l15 = lane & 15, g4 = lane >> 4;
    const int m0 = blockIdx.y * 64, n0 = blockIdx.x * 128;
    const int wm0 = (w & 1) * 32, wn0 = (w >> 1) * 64;
    f32x4 acc[2][4];
    #pragma unroll
    for (int mt = 0; mt < 2; ++mt)
        #pragma unroll
        for (int nt = 0; nt < 4; ++nt)
            acc[mt][nt] = (f32x4){0.f, 0.f, 0.f, 0.f};

    const int ar = t >> 2, ag = t & 3;       // A: row ar, k-granule ag
    for (int k0 = 0; k0 < 512; k0 += 32) {
        __syncthreads();
        {   // stage A (64 rows x 32 k, split on the fly)
            const float* src = &x[(m0 + ar) * 512 + k0 + ag * 8];
            float4 f0 = *(const float4*)&src[0];
            float4 f1 = *(const float4*)&src[4];
            uint4 h, l;
            split8(f0, f1, h, l);
            int slot = ar * 5 + ag;
            *(uint4*)&Ah[slot * 8] = h;
            *(uint4*)&Al[slot * 8] = l;
        }
        #pragma unroll
        for (int u = 0; u < 2; ++u) {        // stage B (128 n x 32 k, pre-split)
            int s = u * 256 + t;
            int n = s >> 2, g = s & 3;
            int srco = (n0 + n) * 512 + k0 + g * 8;
            int slot = n * 5 + g;
            *(uint4*)&Bh[slot * 8] = *(const uint4*)&W01h[srco];
            *(uint4*)&Bl[slot * 8] = *(const uint4*)&W01l[srco];
        }
        __syncthreads();
        bf16x8 ah[2], al[2], bh[4], bl[4];
        #pragma unroll
        for (int mt = 0; mt < 2; ++mt) {
            int slot = (wm0 + mt * 16 + l15) * 5 + g4;
            ah[mt] = *(const bf16x8*)&Ah[slot * 8];
            al[mt] = *(const bf16x8*)&Al[slot * 8];
        }
        #pragma unroll
        for (int nt = 0; nt < 4; ++nt) {
            int slot = (wn0 + nt * 16 + l15) * 5 + g4;
            bh[nt] = *(const bf16x8*)&Bh[slot * 8];
            bl[nt] = *(const bf16x8*)&Bl[slot * 8];
        }
        #pragma unroll
        for (int mt = 0; mt < 2; ++mt)
            #pragma unroll
            for (int nt = 0; nt < 4; ++nt) {
                acc[mt][nt] = __builtin_amdgcn_mfma_f32_16x16x32_bf16(ah[mt], bh[nt], acc[mt][nt], 0, 0, 0);
                acc[mt][nt] = __builtin_amdgcn_mfma_f32_16x16x32_bf16(al[mt], bh[nt], acc[mt][nt], 0, 0, 0);
                acc[mt][nt] = __builtin_amdgcn_mfma_f32_16x16x32_bf16(ah[mt], bl[nt], acc[mt][nt], 0, 0, 0);
            }
    }
    ush* oh = (n0 == 0) ? qh : kh;
    ush* ol = (n0 == 0) ? ql : kl;
    #pragma unroll
    for (int mt = 0; mt < 2; ++mt)
        #pragma unroll
        for (int nt = 0; nt < 4; ++nt) {
            int col = wn0 + nt * 16 + l15;
            int rowb = m0 + wm0 + mt * 16 + g4 * 4;
            #pragma unroll
            for (int reg = 0; reg < 4; ++reg) {
                float v = acc[mt][nt][reg];
                unsigned u = __float_as_uint(v);
                ush h = (ush)(u >> 16);
                ush lo = f2bf(v - __uint_as_float(u & 0xFFFF0000u));
                oh[(rowb + reg) * 128 + col] = h;
                ol[(rowb + reg) * 128 + col] = lo;
            }
        }
}

// ---------------------------------------------------------------------------
// time path (xt bf16)
// ---------------------------------------------------------------------------
__global__ __launch_bounds__(256) void time_part1(const ush* __restrict__ xtb,
                                                  float* __restrict__ pP,
                                                  float* __restrict__ pQ) {
    int d = blockIdx.x * 256 + threadIdx.x;
    int r0 = blockIdx.y * 128;
    float sp = 0.f, sq = 0.f;
    for (int r = 0; r < 128; ++r) {
        float v = bf2f(xtb[(r0 + r) * 512 + d]);
        sp += v;
        sq += (float)(r0 + r) * v;
    }
    pP[blockIdx.y * 512 + d] = sp;
    pQ[blockIdx.y * 512 + d] = sq;
}

__global__ __launch_bounds__(512) void time_part2(float* __restrict__ pP,
                                                  float* __restrict__ pQ,
                                                  float* __restrict__ Ad,
                                                  float* __restrict__ Qt) {
    int d = threadIdx.x;
    float rp = 0.f, rq = 0.f;
    for (int c = 0; c < 64; ++c) {
        int idx = c * 512 + d;
        float p = pP[idx], qv = pQ[idx];
        pP[idx] = rp; pQ[idx] = rq;
        rp += p; rq += qv;
    }
    Ad[d] = rp; Qt[d] = rq;
}

__global__ __launch_bounds__(256) void time_part3(const ush* __restrict__ xtb,
                                                  const float* __restrict__ pP,
                                                  const float* __restrict__ pQ,
                                                  const float* __restrict__ Ad,
                                                  const float* __restrict__ Qt,
                                                  float* __restrict__ out) {
    int d = blockIdx.x * 256 + threadIdx.x;
    int r0 = blockIdx.y * 128;
    float P = pP[blockIdx.y * 512 + d];
    float Q = pQ[blockIdx.y * 512 + d];
    float A = Ad[d], Qtot = Qt[d];
    for (int r = 0; r < 128; ++r) {
        int i = r0 + r;
        float v = bf2f(xtb[i * 512 + d]);
        P += v;
        float fi = (float)i;
        Q += fi * v;
        float B = 2.f * fi * P - 2.f * Q + Qtot - fi * A;
        int Si = 67108864 - (i * (i + 1)) / 2 - ((8191 - i) * (8192 - i)) / 2;
        float T = (8192.f * A - B) / (float)Si;
        out[i * 512 + d] = 0.5f * T;
    }
}

// ---------------------------------------------------------------------------
// pass1: softmax stats, j-split x8. grid (8 jchunks, 256 iblocks).
// Per-lane (m,l) running stats; one butterfly merge at end.
// ---------------------------------------------------------------------------
__global__ __launch_bounds__(256) void pass1(const ush* __restrict__ qhg,
                                             const ush* __restrict__ qlg,
                                             const ush* __restrict__ khg,
                                             const ush* __restrict__ klg,
                                             float* __restrict__ pm,
                                             float* __restrict__ pl) {
    __shared__ __align__(16) ush Kh[32 * 128];
    __shared__ __align__(16) ush Kl[32 * 128];
    __shared__ float sm_[2][32], sl_[2][32];
    const int t = threadIdx.x;
    const int lane = t & 63, w = t >> 6;
    const int rt = w & 1, ct = w >> 1;
    const int i0 = blockIdx.y * 32;
    const int jbase = blockIdx.x * 1024;
    const int l15 = lane & 15, g = lane >> 4;

    bf16x8 Qh[4], Ql[4];
    {
        int qrow = i0 + rt * 16 + l15;
        #pragma unroll
        for (int kt = 0; kt < 4; ++kt) {
            Qh[kt] = *(const bf16x8*)&qhg[qrow * 128 + kt * 32 + g * 8];
            Ql[kt] = *(const bf16x8*)&qlg[qrow * 128 + kt * 32 + g * 8];
        }
    }
    float m_run[4] = {-INFINITY, -INFINITY, -INFINITY, -INFINITY};
    float l_run[4] = {0.f, 0.f, 0.f, 0.f};

    for (int jt = 0; jt < 32; ++jt) {
        int j0 = jbase + jt * 32;
        __syncthreads();
        #pragma unroll
        for (int u = 0; u < 2; ++u) {
            int s = u * 256 + t;
            int n = s >> 4, gl = (s & 15) ^ (n & 15);
            int src = (j0 + n) * 128 + gl * 8;
            *(uint4*)&Kh[s * 8] = *(const uint4*)&khg[src];
            *(uint4*)&Kl[s * 8] = *(const uint4*)&klg[src];
        }
        __syncthreads();

        bf16x8 kbh[4], kbl[4];
        {
            int n = ct * 16 + l15;
            #pragma unroll
            for (int kt = 0; kt < 4; ++kt) {
                int slot = n * 16 + ((kt * 4 + g) ^ (n & 15));
                kbh[kt] = *(const bf16x8*)&Kh[slot * 8];
                kbl[kt] = *(const bf16x8*)&Kl[slot * 8];
            }
        }
        f32x4 s4 = {0.f, 0.f, 0.f, 0.f};
        #pragma unroll
        for (int kt = 0; kt < 4; ++kt) s4 = __builtin_amdgcn_mfma_f32_16x16x32_bf16(Qh[kt], kbh[kt], s4, 0, 0, 0);
        #pragma unroll
        for (int kt = 0; kt < 4; ++kt) s4 = __builtin_amdgcn_mfma_f32_16x16x32_bf16(Ql[kt], kbh[kt], s4, 0, 0, 0);
        #pragma unroll
        for (int kt = 0; kt < 4; ++kt) s4 = __builtin_amdgcn_mfma_f32_16x16x32_bf16(Qh[kt], kbl[kt], s4, 0, 0, 0);

        #pragma unroll
        for (int reg = 0; reg < 4; ++reg) {    // per-lane online (m,l) only
            float s = s4[reg];
            float mn = fmaxf(m_run[reg], s);
            l_run[reg] = l_run[reg] * __expf(m_run[reg] - mn) + __expf(s - mn);
            m_run[reg] = mn;
        }
    }
    // butterfly merge over the 16 col-lanes
    #pragma unroll
    for (int st = 1; st < 16; st <<= 1) {
        #pragma unroll
        for (int reg = 0; reg < 4; ++reg) {
            float mo = __shfl_xor(m_run[reg], st);
            float lo = __shfl_xor(l_run[reg], st);
            float mn = fmaxf(m_run[reg], mo);
            l_run[reg] = l_run[reg] * __expf(m_run[reg] - mn) + lo * __expf(mo - mn);
            m_run[reg] = mn;
        }
    }
    if (l15 == 0) {
        #pragma unroll
        for (int reg = 0; reg < 4; ++reg) {
            sm_[ct][rt * 16 + g * 4 + reg] = m_run[reg];
            sl_[ct][rt * 16 + g * 4 + reg] = l_run[reg];
        }
    }
    __syncthreads();
    if (t < 32) {
        float M = fmaxf(sm_[0][t], sm_[1][t]);
        float l = sl_[0][t] * __expf(sm_[0][t] - M) + sl_[1][t] * __expf(sm_[1][t] - M);
        pm[blockIdx.x * 8192 + i0 + t] = M;
        pl[blockIdx.x * 8192 + i0 + t] = l;
    }
}

__global__ __launch_bounds__(256) void merge_stats(const float* __restrict__ pm,
                                                   const float* __restrict__ pl,
                                                   float* __restrict__ Mrow,
                                                   float* __restrict__ Rl) {
    int i = blockIdx.x * 256 + threadIdx.x;
    float M = pm[i];
    #pragma unroll
    for (int js = 1; js < 8; ++js) M = fmaxf(M, pm[js * 8192 + i]);
    float l = 0.f;
    #pragma unroll
    for (int js = 0; js < 8; ++js) l += pl[js * 8192 + i] * __expf(pm[js * 8192 + i] - M);
    Mrow[i] = M;
    Rl[i] = 1.0f / l;
}

// ---------------------------------------------------------------------------
// pass2: O_partial = exp(S-M)/l @ V, transposed PV.
// R9: DOUBLE-BUFFERED staging via __builtin_amdgcn_global_load_lds (16B).
// Separate __shared__ arrays per buffer + 2x-unrolled loop keeps buffer
// identity static (alias-analysis friendly — no forced vmcnt before ds_read).
// Loads for iter jt+1 issue right after barrier A of iter jt; they get the
// whole S+B+PV (~800 cyc) to land. R4/R6's serial stage->drain chain (the
// ~4000 cyc/iter stall at 1 block/CU) is removed. BM=64, grid 256 (XCD
// swizzle), bf16 partials + merge_k — the proven 274 us shape otherwise.
// LDS 101 KB (gfx950 allows 160 KB/wg) -> 1 block/CU; dbuf replaces
// co-residency.
// ---------------------------------------------------------------------------
__global__ __launch_bounds__(256, 1) void pass2(const ush* __restrict__ qhg,
                                                const ush* __restrict__ qlg,
                                                const ush* __restrict__ khg,
                                                const ush* __restrict__ klg,
                                                const ush* __restrict__ vtg,
                                                const float* __restrict__ Mrow,
                                                const float* __restrict__ Rl,
                                                ush* __restrict__ part0,
                                                ush* __restrict__ part1) {
    __shared__ __align__(16) ush Kh0[32 * 128];   // 8 KB
    __shared__ __align__(16) ush Kl0[32 * 128];   // 8 KB
    __shared__ __align__(16) ush Vt0[512 * 32];   // 32 KB
    __shared__ __align__(16) ush Kh1[32 * 128];   // 8 KB
    __shared__ __align__(16) ush Kl1[32 * 128];   // 8 KB
    __shared__ __align__(16) ush Vt1[512 * 32];   // 32 KB
    __shared__ __align__(16) ush P[64 * 40];      // 5 KB

    const int t = threadIdx.x;
    const int lane = t & 63, w = t >> 6;
    const int l15 = lane & 15, g = lane >> 4;
    const int b = blockIdx.x;
    const int xcd = b & 7, lid = b >> 3;
    const int jhalf = xcd >> 2;                  // XCDs 0-3 -> half 0, 4-7 -> half 1
    const int strip = (xcd & 3) * 32 + lid;      // 0..127
    const int i0 = strip * 64;
    const int jbase = jhalf * 4096;

    bf16x8 Qh[2][4], Ql[2][4];
    #pragma unroll
    for (int rt = 0; rt < 2; ++rt) {
        int qrow = i0 + 32 * (w & 1) + rt * 16 + l15;
        #pragma unroll
        for (int kt = 0; kt < 4; ++kt) {
            Qh[rt][kt] = *(const bf16x8*)&qhg[qrow * 128 + kt * 32 + g * 8];
            Ql[rt][kt] = *(const bf16x8*)&qlg[qrow * 128 + kt * 32 + g * 8];
        }
    }
    float Mv[2][4], Rv[2][4];
    #pragma unroll
    for (int rt = 0; rt < 2; ++rt)
        #pragma unroll
        for (int reg = 0; reg < 4; ++reg) {
            int row = i0 + 32 * (w & 1) + rt * 16 + g * 4 + reg;
            Mv[rt][reg] = Mrow[row];
            Rv[rt][reg] = Rl[row];
        }

    f32x4 acc[8][4];
    #pragma unroll
    for (int mt = 0; mt < 8; ++mt)
        #pragma unroll
        for (int nt = 0; nt < 4; ++nt)
            acc[mt][nt] = (f32x4){0.f, 0.f, 0.f, 0.f};

    // async stage one 32-key tile into a buffer set (LDS dst: uniform+lane*16)
    auto stage = [&](ush* KhD, ush* KlD, ush* VtD, int j0) {
        #pragma unroll
        for (int u = 0; u < 2; ++u) {
            int s = u * 256 + t;
            int n = s >> 4, gl = (s & 15) ^ (n & 15);
            int src = (j0 + n) * 128 + gl * 8;
            cp16(&khg[src], &KhD[s * 8]);
            cp16(&klg[src], &KlD[s * 8]);
        }
        #pragma unroll
        for (int u = 0; u < 8; ++u) {
            int s = u * 256 + t;
            int c = s >> 2, gl = (s & 3) ^ ((c >> 1) & 3);
            cp16(&vtg[c * 8192 + j0 + gl * 8], &VtD[s * 8]);
        }
    };

    // one pipeline iteration: compute from C-set, prefetch into N-set
    auto iter = [&](const ush* KhC, const ush* KlC, const ush* VtC,
                    ush* KhN, ush* KlN, ush* VtN, int jt) {
        __syncthreads();                       // (A) C-set loads complete; prev PV reads done
        if (jt < 127) stage(KhN, KlN, VtN, jbase + (jt + 1) * 32);

        // ---- S = Q K^T ----
        bf16x8 kbh[4], kbl[4];
        {
            int n = (w >> 1) * 16 + l15;
            #pragma unroll
            for (int kt = 0; kt < 4; ++kt) {
                int slot = n * 16 + ((kt * 4 + g) ^ (n & 15));
                kbh[kt] = *(const bf16x8*)&KhC[slot * 8];
                kbl[kt] = *(const bf16x8*)&KlC[slot * 8];
            }
        }
        #pragma unroll
        for (int rt = 0; rt < 2; ++rt) {
            f32x4 s4 = {0.f, 0.f, 0.f, 0.f};
            #pragma unroll
            for (int kt = 0; kt < 4; ++kt) s4 = __builtin_amdgcn_mfma_f32_16x16x32_bf16(Qh[rt][kt], kbh[kt], s4, 0, 0, 0);
            #pragma unroll
            for (int kt = 0; kt < 4; ++kt) s4 = __builtin_amdgcn_mfma_f32_16x16x32_bf16(Ql[rt][kt], kbh[kt], s4, 0, 0, 0);
            #pragma unroll
            for (int kt = 0; kt < 4; ++kt) s4 = __builtin_amdgcn_mfma_f32_16x16x32_bf16(Qh[rt][kt], kbl[kt], s4, 0, 0, 0);
            #pragma unroll
            for (int reg = 0; reg < 4; ++reg) {
                float p = __expf(s4[reg] - Mv[rt][reg]) * Rv[rt][reg];
                int row = 32 * (w & 1) + rt * 16 + g * 4 + reg;
                int col = (w >> 1) * 16 + l15;
                P[row * 40 + col] = f2bf(p);
            }
        }
        __syncthreads();                       // (B) P visible

        // ---- O^T += Vt_tile * P^T ----
        bf16x8 Pb[4];
        #pragma unroll
        for (int nt = 0; nt < 4; ++nt)
            Pb[nt] = *(const bf16x8*)&P[(nt * 16 + l15) * 40 + g * 8];
        #pragma unroll
        for (int mt = 0; mt < 8; ++mt) {
            int c = w * 128 + mt * 16 + l15;
            int slot = c * 4 + (g ^ ((c >> 1) & 3));
            bf16x8 vf = *(const bf16x8*)&VtC[slot * 8];
            #pragma unroll
            for (int nt = 0; nt < 4; ++nt)
                acc[mt][nt] = __builtin_amdgcn_mfma_f32_16x16x32_bf16(vf, Pb[nt], acc[mt][nt], 0, 0, 0);
        }
    };

    stage(Kh0, Kl0, Vt0, jbase);               // prologue: fill set 0
    for (int jj = 0; jj < 64; ++jj) {
        iter(Kh0, Kl0, Vt0, Kh1, Kl1, Vt1, 2 * jj);
        iter(Kh1, Kl1, Vt1, Kh0, Kl0, Vt0, 2 * jj + 1);
    }

    ush* prt = (jhalf == 0) ? part0 : part1;
    #pragma unroll
    for (int mt = 0; mt < 8; ++mt)
        #pragma unroll
        for (int nt = 0; nt < 4; ++nt) {
            int qrow = i0 + nt * 16 + l15;
            int vcol = w * 128 + mt * 16 + g * 4;
            uint2 pk;
            pk.x = (unsigned)f2bf(acc[mt][nt][0]) | ((unsigned)f2bf(acc[mt][nt][1]) << 16);
            pk.y = (unsigned)f2bf(acc[mt][nt][2]) | ((unsigned)f2bf(acc[mt][nt][3]) << 16);
            *(uint2*)&prt[qrow * 512 + vcol] = pk;
        }
}

// ---------------------------------------------------------------------------
// merge_k — out += 0.5 * (part0 + part1)
// ---------------------------------------------------------------------------
__global__ __launch_bounds__(256) void merge_k(const ush* __restrict__ p0,
                                               const ush* __restrict__ p1,
                                               float* __restrict__ out) {
    int base = (blockIdx.x * 256 + threadIdx.x) * 8;
    uint4 a = *(const uint4*)&p0[base];
    uint4 b = *(const uint4*)&p1[base];
    float4 o0 = *(float4*)&out[base];
    float4 o1 = *(float4*)&out[base + 4];
    unsigned av[4] = {a.x, a.y, a.z, a.w};
    unsigned bv[4] = {b.x, b.y, b.z, b.w};
    float r[8];
    #pragma unroll
    for (int i = 0; i < 4; ++i) {
        r[2 * i + 0] = 0.5f * (bf2f((ush)(av[i] & 0xFFFF)) + bf2f((ush)(bv[i] & 0xFFFF)));
        r[2 * i + 1] = 0.5f * (bf2f((ush)(av[i] >> 16)) + bf2f((ush)(bv[i] >> 16)));
    }
    o0.x += r[0]; o0.y += r[1]; o0.z += r[2]; o0.w += r[3];
    o1.x += r[4]; o1.y += r[5]; o1.z += r[6]; o1.w += r[7];
    *(float4*)&out[base] = o0;
    *(float4*)&out[base + 4] = o1;
}

// ---------------------------------------------------------------------------
extern "C" void kernel_launch(void* const* d_in, const int* in_sizes, int n_in,
                              void* d_out, int out_size, void* d_ws, size_t ws_size,
                              hipStream_t stream) {
    const float* x  = (const float*)d_in[0];
    const float* W0 = (const float*)d_in[1];
    const float* W1 = (const float*)d_in[2];
    const float* wm = (const float*)d_in[3];
    const float* wt = (const float*)d_in[4];
    float* out = (float*)d_out;
    float* ws  = (float*)d_ws;

    // Region A
    ush* vtg = (ush*)(ws + 0);
    // Region B: xt bf16, then stats overlay after time path
    ush* xtb  = (ush*)(ws + 2097152);
    float* Mr = ws + 2097152;
    float* Rl = ws + 2105344;
    float* pm = ws + 2113536;
    float* pl = ws + 2179072;
    // Region C: weights (early) -> partials (late)
    ush* W01h = (ush*)(ws + 4194304);
    ush* W01l = (ush*)(ws + 4259840);
    ush* wmTh = (ush*)(ws + 4325376);
    ush* wmTl = (ush*)(ws + 4456448);
    ush* wtTh = (ush*)(ws + 4587520);
    ush* wtTl = (ush*)(ws + 4718592);
    ush* part0 = (ush*)(ws + 4194304);
    ush* part1 = (ush*)(ws + 6291456);
    // Region D
    ush* qh = (ush*)(ws + 8388608);
    ush* ql = (ush*)(ws + 8912896);
    ush* kh = (ush*)(ws + 9437184);
    ush* kl = (ush*)(ws + 9961472);
    // Region E
    float* pP = ws + 10485760;
    float* pQ = ws + 10518528;
    float* Ad = ws + 10551296;
    float* Qt = ws + 10551808;

    cast_w01   <<<dim3(64),       256, 0, stream>>>(W0, W1, W01h, W01l);
    cast_wT    <<<dim3(8, 8, 2),  256, 0, stream>>>(wm, wt, wmTh, wmTl, wtTh, wtTl);
    gemm_xv    <<<dim3(4, 64, 2), 256, 0, stream>>>(x, wmTh, wmTl, wtTh, wtTl, vtg, xtb);
    gemm_qk    <<<dim3(2, 128),   256, 0, stream>>>(x, W01h, W01l, qh, ql, kh, kl);
    time_part1 <<<dim3(2, 64),    256, 0, stream>>>(xtb, pP, pQ);
    time_part2 <<<dim3(1),        512, 0, stream>>>(pP, pQ, Ad, Qt);
    time_part3 <<<dim3(2, 64),    256, 0, stream>>>(xtb, pP, pQ, Ad, Qt, out);
    pass1      <<<dim3(8, 256),   256, 0, stream>>>(qh, ql, kh, kl, pm, pl);
    merge_stats<<<dim3(32),       256, 0, stream>>>(pm, pl, Mr, Rl);
    pass2      <<<dim3(256),      256, 0, stream>>>(qh, ql, kh, kl, vtg, Mr, Rl, part0, part1);
    merge_k    <<<dim3(2048),     256, 0, stream>>>(part0, part1, out);
}

// Round 10
// 429.225 us; speedup vs baseline: 1.5491x; 1.0001x over previous
//
#include <hip/hip_runtime.h>
#include <math.h>

// Problem constants
#define NN 8192
#define INS 512
#define FEAT 128

typedef unsigned short ush;
typedef short bf16x8 __attribute__((ext_vector_type(8)));
typedef float f32x4 __attribute__((ext_vector_type(4)));

__device__ __forceinline__ ush f2bf(float f) {           // RNE fp32->bf16
    unsigned u = __float_as_uint(f);
    unsigned r = (u + 0x7FFFu + ((u >> 16) & 1u)) >> 16;
    return (ush)r;
}
__device__ __forceinline__ float bf2f(ush h) {
    return __uint_as_float(((unsigned)h) << 16);
}
// async 16B global -> LDS (gfx950 global_load_lds_dwordx4). LDS dst must be
// wave-uniform-base + lane*16 — our staging layouts satisfy this by design.
__device__ __forceinline__ void cp16(const ush* g, ush* l) {
    __builtin_amdgcn_global_load_lds(
        (const __attribute__((address_space(1))) void*)g,
        (__attribute__((address_space(3))) void*)l, 16, 0, 0);
}
// trunc-split 8 floats into hi bf16 (truncation) + lo bf16 (RNE of residual).
__device__ __forceinline__ void split8(float4 f0, float4 f1, uint4& h, uint4& l) {
    float f[8] = {f0.x, f0.y, f0.z, f0.w, f1.x, f1.y, f1.z, f1.w};
    unsigned hu[8], lu[8];
    #pragma unroll
    for (int j = 0; j < 8; ++j) {
        unsigned u = __float_as_uint(f[j]);
        hu[j] = u >> 16;
        float lo = f[j] - __uint_as_float(u & 0xFFFF0000u);
        lu[j] = (unsigned)f2bf(lo);
    }
    h.x = hu[0] | (hu[1] << 16); h.y = hu[2] | (hu[3] << 16);
    h.z = hu[4] | (hu[5] << 16); h.w = hu[6] | (hu[7] << 16);
    l.x = lu[0] | (lu[1] << 16); l.y = lu[2] | (lu[3] << 16);
    l.z = lu[4] | (lu[5] << 16); l.w = lu[6] | (lu[7] << 16);
}

// ws layout (float offsets), total = 10,552,320 floats = 42.2 MB.
//  A [0,2097152)        : vtg bf16 [512][8192]
//  B [2097152,4194304)  : xt bf16 -> (after time path) Mrow/Rl/pm/pl
//  C [4194304,8388608)  : weights hi/lo (early) -> part0/part1 bf16 (pass2)
//  D [8388608,10485760) : qh,ql,kh,kl bf16 [8192][128]
//  E [10485760,10552320): pP,pQ,Ad,Qt fp32

// ---------------------------------------------------------------------------
// cast_w01: W0,W1 [128][512] fp32 -> W01h/W01l [256][512] bf16
// ---------------------------------------------------------------------------
__global__ __launch_bounds__(256) void cast_w01(const float* __restrict__ W0,
                                                const float* __restrict__ W1,
                                                ush* __restrict__ W01h,
                                                ush* __restrict__ W01l) {
    int idx = (blockIdx.x * 256 + threadIdx.x) * 8;      // 131072 elements total
    int r = idx >> 9, c = idx & 511;
    const float* src = (r < 128) ? &W0[r * 512 + c] : &W1[(r - 128) * 512 + c];
    float4 f0 = *(const float4*)src;
    float4 f1 = *(const float4*)(src + 4);
    uint4 h, l;
    split8(f0, f1, h, l);
    *(uint4*)&W01h[idx] = h;
    *(uint4*)&W01l[idx] = l;
}

// ---------------------------------------------------------------------------
// cast_wT: wm/wt [512k][512n] fp32 -> transposed hi/lo bf16 [512n][512k]
// ---------------------------------------------------------------------------
__global__ __launch_bounds__(256) void cast_wT(const float* __restrict__ wm,
                                               const float* __restrict__ wt,
                                               ush* __restrict__ wmTh, ush* __restrict__ wmTl,
                                               ush* __restrict__ wtTh, ush* __restrict__ wtTl) {
    const float* src = blockIdx.z ? wt : wm;
    ush* oh = blockIdx.z ? wtTh : wmTh;
    ush* ol = blockIdx.z ? wtTl : wmTl;
    __shared__ float T[64][65];
    const int t = threadIdx.x;
    const int k0 = blockIdx.y * 64, n0 = blockIdx.x * 64;
    #pragma unroll
    for (int u = 0; u < 4; ++u) {
        int idx = u * 256 + t;
        int r = idx >> 4, c4 = (idx & 15) * 4;
        *(float4*)&T[r][c4] = *(const float4*)&src[(k0 + r) * 512 + n0 + c4];
    }
    __syncthreads();
    #pragma unroll
    for (int u = 0; u < 4; ++u) {
        int idx = u * 256 + t;
        int a = idx >> 4, b4 = (idx & 15) * 4;   // out row n0+a, k cols k0+b4..+3
        unsigned hu[4], lu[4];
        #pragma unroll
        for (int j = 0; j < 4; ++j) {
            float f = T[b4 + j][a];
            unsigned uu = __float_as_uint(f);
            hu[j] = uu >> 16;
            lu[j] = (unsigned)f2bf(f - __uint_as_float(uu & 0xFFFF0000u));
        }
        uint2 hp, lp;
        hp.x = hu[0] | (hu[1] << 16); hp.y = hu[2] | (hu[3] << 16);
        lp.x = lu[0] | (lu[1] << 16); lp.y = lu[2] | (lu[3] << 16);
        *(uint2*)&oh[(n0 + a) * 512 + k0 + b4] = hp;
        *(uint2*)&ol[(n0 + a) * 512 + k0 + b4] = lp;
    }
}

// ---------------------------------------------------------------------------
// gemm_xv: C = x @ w (hi/lo bf16 MFMA, 3 terms), 128x128 tile, BK=32.
// z=0: w=weight, writes vtg TRANSPOSED (bf16). z=1: w=weight_time, writes xt.
// ---------------------------------------------------------------------------
__global__ __launch_bounds__(256) void gemm_xv(const float* __restrict__ x,
    const ush* __restrict__ wmTh, const ush* __restrict__ wmTl,
    const ush* __restrict__ wtTh, const ush* __restrict__ wtTl,
    ush* __restrict__ vtg, ush* __restrict__ xtb) {
    const bool isV = (blockIdx.z == 0);
    const ush* Bhg = isV ? wmTh : wtTh;
    const ush* Blg = isV ? wmTl : wtTl;
    __shared__ __align__(16) ush sm[20480];   // 40 KB; reused as LT in epilogue
    ush* Ah = sm;
    ush* Al = sm + 5120;
    ush* Bh = sm + 10240;
    ush* Bl = sm + 15360;
    const int t = threadIdx.x;
    const int lane = t & 63, w = t >> 6;
    const int l15 = lane & 15, g4 = lane >> 4;
    const int m0 = blockIdx.y * 128, n0 = blockIdx.x * 128;
    const int wm0 = (w & 1) * 64, wn0 = (w >> 1) * 64;
    f32x4 acc[4][4];
    #pragma unroll
    for (int mt = 0; mt < 4; ++mt)
        #pragma unroll
        for (int nt = 0; nt < 4; ++nt)
            acc[mt][nt] = (f32x4){0.f, 0.f, 0.f, 0.f};

    const int am = t >> 1, akh = (t & 1) * 16;
    for (int k0 = 0; k0 < 512; k0 += 32) {
        __syncthreads();
        {   // stage A (x fp32 -> hi/lo bf16 granules)
            const float* src = &x[(m0 + am) * 512 + k0 + akh];
            float4 f0 = *(const float4*)&src[0];
            float4 f1 = *(const float4*)&src[4];
            float4 f2 = *(const float4*)&src[8];
            float4 f3 = *(const float4*)&src[12];
            uint4 h0, l0, h1, l1;
            split8(f0, f1, h0, l0);
            split8(f2, f3, h1, l1);
            int s0 = am * 5 + (akh >> 3);
            *(uint4*)&Ah[s0 * 8] = h0; *(uint4*)&Ah[(s0 + 1) * 8] = h1;
            *(uint4*)&Al[s0 * 8] = l0; *(uint4*)&Al[(s0 + 1) * 8] = l1;
        }
        #pragma unroll
        for (int u = 0; u < 2; ++u) {   // stage B (pre-split bf16)
            int s = u * 256 + t;
            int n = s >> 2, g = s & 3;
            int srco = (n0 + n) * 512 + k0 + g * 8;
            int slot = n * 5 + g;
            *(uint4*)&Bh[slot * 8] = *(const uint4*)&Bhg[srco];
            *(uint4*)&Bl[slot * 8] = *(const uint4*)&Blg[srco];
        }
        __syncthreads();
        bf16x8 ah[4], al[4], bh[4], bl[4];
        #pragma unroll
        for (int mt = 0; mt < 4; ++mt) {
            int slot = (wm0 + mt * 16 + l15) * 5 + g4;
            ah[mt] = *(const bf16x8*)&Ah[slot * 8];
            al[mt] = *(const bf16x8*)&Al[slot * 8];
        }
        #pragma unroll
        for (int nt = 0; nt < 4; ++nt) {
            int slot = (wn0 + nt * 16 + l15) * 5 + g4;
            bh[nt] = *(const bf16x8*)&Bh[slot * 8];
            bl[nt] = *(const bf16x8*)&Bl[slot * 8];
        }
        #pragma unroll
        for (int mt = 0; mt < 4; ++mt)
            #pragma unroll
            for (int nt = 0; nt < 4; ++nt) {
                acc[mt][nt] = __builtin_amdgcn_mfma_f32_16x16x32_bf16(ah[mt], bh[nt], acc[mt][nt], 0, 0, 0);
                acc[mt][nt] = __builtin_amdgcn_mfma_f32_16x16x32_bf16(al[mt], bh[nt], acc[mt][nt], 0, 0, 0);
                acc[mt][nt] = __builtin_amdgcn_mfma_f32_16x16x32_bf16(ah[mt], bl[nt], acc[mt][nt], 0, 0, 0);
            }
    }

    if (!isV) {   // xt: direct bf16 stores
        #pragma unroll
        for (int mt = 0; mt < 4; ++mt)
            #pragma unroll
            for (int nt = 0; nt < 4; ++nt) {
                int col = n0 + wn0 + nt * 16 + l15;
                int rowb = m0 + wm0 + mt * 16 + g4 * 4;
                #pragma unroll
                for (int reg = 0; reg < 4; ++reg)
                    xtb[(rowb + reg) * 512 + col] = f2bf(acc[mt][nt][reg]);
            }
    } else {      // vtg: transpose through LDS
        __syncthreads();
        #pragma unroll
        for (int mt = 0; mt < 4; ++mt)
            #pragma unroll
            for (int nt = 0; nt < 4; ++nt) {
                int nl = wn0 + nt * 16 + l15;
                int mb = wm0 + mt * 16 + g4 * 4;
                uint2 pk;
                pk.x = (unsigned)f2bf(acc[mt][nt][0]) | ((unsigned)f2bf(acc[mt][nt][1]) << 16);
                pk.y = (unsigned)f2bf(acc[mt][nt][2]) | ((unsigned)f2bf(acc[mt][nt][3]) << 16);
                *(uint2*)&sm[nl * 136 + mb] = pk;
            }
        __syncthreads();
        int a = t >> 1, off = (t & 1) * 64;
        #pragma unroll
        for (int u = 0; u < 8; ++u)
            *(uint4*)&vtg[(n0 + a) * 8192 + m0 + off + u * 8] =
                *(const uint4*)&sm[a * 136 + off + u * 8];
    }
}

// ---------------------------------------------------------------------------
// gemm_qk: [q|k] = x @ [W0|W1]^T (hi/lo MFMA) -> qh/ql/kh/kl
// BM=64, BN=128 -> grid (2,128) = 256 blocks.
// ---------------------------------------------------------------------------
__global__ __launch_bounds__(256) void gemm_qk(const float* __restrict__ x,
    const ush* __restrict__ W01h, const ush* __restrict__ W01l,
    ush* __restrict__ qh, ush* __restrict__ ql,
    ush* __restrict__ kh, ush* __restrict__ kl) {
    __shared__ __align__(16) ush sm[15360];   // Ah 2560 | Al 2560 | Bh 5120 | Bl 5120
    ush* Ah = sm;
    ush* Al = sm + 2560;
    ush* Bh = sm + 5120;
    ush* Bl = sm + 10240;
    const int t = threadIdx.x;
    const int lane = t & 63, w = t >> 6;
    const int l15 = lane & 15, g4 = lane >> 4;
    const int m0 = blockIdx.y * 64, n0 = blockIdx.x * 128;
    const int wm0 = (w & 1) * 32, wn0 = (w >> 1) * 64;
    f32x4 acc[2][4];
    #pragma unroll
    for (int mt = 0; mt < 2; ++mt)
        #pragma unroll
        for (int nt = 0; nt < 4; ++nt)
            acc[mt][nt] = (f32x4){0.f, 0.f, 0.f, 0.f};

    const int ar = t >> 2, ag = t & 3;       // A: row ar, k-granule ag
    for (int k0 = 0; k0 < 512; k0 += 32) {
        __syncthreads();
        {   // stage A (64 rows x 32 k, split on the fly)
            const float* src = &x[(m0 + ar) * 512 + k0 + ag * 8];
            float4 f0 = *(const float4*)&src[0];
            float4 f1 = *(const float4*)&src[4];
            uint4 h, l;
            split8(f0, f1, h, l);
            int slot = ar * 5 + ag;
            *(uint4*)&Ah[slot * 8] = h;
            *(uint4*)&Al[slot * 8] = l;
        }
        #pragma unroll
        for (int u = 0; u < 2; ++u) {        // stage B (128 n x 32 k, pre-split)
            int s = u * 256 + t;
            int n = s >> 2, g = s & 3;
            int srco = (n0 + n) * 512 + k0 + g * 8;
            int slot = n * 5 + g;
            *(uint4*)&Bh[slot * 8] = *(const uint4*)&W01h[srco];
            *(uint4*)&Bl[slot * 8] = *(const uint4*)&W01l[srco];
        }
        __syncthreads();
        bf16x8 ah[2], al[2], bh[4], bl[4];
        #pragma unroll
        for (int mt = 0; mt < 2; ++mt) {
            int slot = (wm0 + mt * 16 + l15) * 5 + g4;
            ah[mt] = *(const bf16x8*)&Ah[slot * 8];
            al[mt] = *(const bf16x8*)&Al[slot * 8];
        }
        #pragma unroll
        for (int nt = 0; nt < 4; ++nt) {
            int slot = (wn0 + nt * 16 + l15) * 5 + g4;
            bh[nt] = *(const bf16x8*)&Bh[slot * 8];
            bl[nt] = *(const bf16x8*)&Bl[slot * 8];
        }
        #pragma unroll
        for (int mt = 0; mt < 2; ++mt)
            #pragma unroll
            for (int nt = 0; nt < 4; ++nt) {
                acc[mt][nt] = __builtin_amdgcn_mfma_f32_16x16x32_bf16(ah[mt], bh[nt], acc[mt][nt], 0, 0, 0);
                acc[mt][nt] = __builtin_amdgcn_mfma_f32_16x16x32_bf16(al[mt], bh[nt], acc[mt][nt], 0, 0, 0);
                acc[mt][nt] = __builtin_amdgcn_mfma_f32_16x16x32_bf16(ah[mt], bl[nt], acc[mt][nt], 0, 0, 0);
            }
    }
    ush* oh = (n0 == 0) ? qh : kh;
    ush* ol = (n0 == 0) ? ql : kl;
    #pragma unroll
    for (int mt = 0; mt < 2; ++mt)
        #pragma unroll
        for (int nt = 0; nt < 4; ++nt) {
            int col = wn0 + nt * 16 + l15;
            int rowb = m0 + wm0 + mt * 16 + g4 * 4;
            #pragma unroll
            for (int reg = 0; reg < 4; ++reg) {
                float v = acc[mt][nt][reg];
                unsigned u = __float_as_uint(v);
                ush h = (ush)(u >> 16);
                ush lo = f2bf(v - __uint_as_float(u & 0xFFFF0000u));
                oh[(rowb + reg) * 128 + col] = h;
                ol[(rowb + reg) * 128 + col] = lo;
            }
        }
}

// ---------------------------------------------------------------------------
// time path (xt bf16)
// ---------------------------------------------------------------------------
__global__ __launch_bounds__(256) void time_part1(const ush* __restrict__ xtb,
                                                  float* __restrict__ pP,
                                                  float* __restrict__ pQ) {
    int d = blockIdx.x * 256 + threadIdx.x;
    int r0 = blockIdx.y * 128;
    float sp = 0.f, sq = 0.f;
    for (int r = 0; r < 128; ++r) {
        float v = bf2f(xtb[(r0 + r) * 512 + d]);
        sp += v;
        sq += (float)(r0 + r) * v;
    }
    pP[blockIdx.y * 512 + d] = sp;
    pQ[blockIdx.y * 512 + d] = sq;
}

__global__ __launch_bounds__(512) void time_part2(float* __restrict__ pP,
                                                  float* __restrict__ pQ,
                                                  float* __restrict__ Ad,
                                                  float* __restrict__ Qt) {
    int d = threadIdx.x;
    float rp = 0.f, rq = 0.f;
    for (int c = 0; c < 64; ++c) {
        int idx = c * 512 + d;
        float p = pP[idx], qv = pQ[idx];
        pP[idx] = rp; pQ[idx] = rq;
        rp += p; rq += qv;
    }
    Ad[d] = rp; Qt[d] = rq;
}

__global__ __launch_bounds__(256) void time_part3(const ush* __restrict__ xtb,
                                                  const float* __restrict__ pP,
                                                  const float* __restrict__ pQ,
                                                  const float* __restrict__ Ad,
                                                  const float* __restrict__ Qt,
                                                  float* __restrict__ out) {
    int d = blockIdx.x * 256 + threadIdx.x;
    int r0 = blockIdx.y * 128;
    float P = pP[blockIdx.y * 512 + d];
    float Q = pQ[blockIdx.y * 512 + d];
    float A = Ad[d], Qtot = Qt[d];
    for (int r = 0; r < 128; ++r) {
        int i = r0 + r;
        float v = bf2f(xtb[i * 512 + d]);
        P += v;
        float fi = (float)i;
        Q += fi * v;
        float B = 2.f * fi * P - 2.f * Q + Qtot - fi * A;
        int Si = 67108864 - (i * (i + 1)) / 2 - ((8191 - i) * (8192 - i)) / 2;
        float T = (8192.f * A - B) / (float)Si;
        out[i * 512 + d] = 0.5f * T;
    }
}

// ---------------------------------------------------------------------------
// pass1: softmax stats, j-split x8. grid (8 jchunks, 256 iblocks).
// Per-lane (m,l) running stats; one butterfly merge at end.
// ---------------------------------------------------------------------------
__global__ __launch_bounds__(256) void pass1(const ush* __restrict__ qhg,
                                             const ush* __restrict__ qlg,
                                             const ush* __restrict__ khg,
                                             const ush* __restrict__ klg,
                                             float* __restrict__ pm,
                                             float* __restrict__ pl) {
    __shared__ __align__(16) ush Kh[32 * 128];
    __shared__ __align__(16) ush Kl[32 * 128];
    __shared__ float sm_[2][32], sl_[2][32];
    const int t = threadIdx.x;
    const int lane = t & 63, w = t >> 6;
    const int rt = w & 1, ct = w >> 1;
    const int i0 = blockIdx.y * 32;
    const int jbase = blockIdx.x * 1024;
    const int l15 = lane & 15, g = lane >> 4;

    bf16x8 Qh[4], Ql[4];
    {
        int qrow = i0 + rt * 16 + l15;
        #pragma unroll
        for (int kt = 0; kt < 4; ++kt) {
            Qh[kt] = *(const bf16x8*)&qhg[qrow * 128 + kt * 32 + g * 8];
            Ql[kt] = *(const bf16x8*)&qlg[qrow * 128 + kt * 32 + g * 8];
        }
    }
    float m_run[4] = {-INFINITY, -INFINITY, -INFINITY, -INFINITY};
    float l_run[4] = {0.f, 0.f, 0.f, 0.f};

    for (int jt = 0; jt < 32; ++jt) {
        int j0 = jbase + jt * 32;
        __syncthreads();
        #pragma unroll
        for (int u = 0; u < 2; ++u) {
            int s = u * 256 + t;
            int n = s >> 4, gl = (s & 15) ^ (n & 15);
            int src = (j0 + n) * 128 + gl * 8;
            *(uint4*)&Kh[s * 8] = *(const uint4*)&khg[src];
            *(uint4*)&Kl[s * 8] = *(const uint4*)&klg[src];
        }
        __syncthreads();

        bf16x8 kbh[4], kbl[4];
        {
            int n = ct * 16 + l15;
            #pragma unroll
            for (int kt = 0; kt < 4; ++kt) {
                int slot = n * 16 + ((kt * 4 + g) ^ (n & 15));
                kbh[kt] = *(const bf16x8*)&Kh[slot * 8];
                kbl[kt] = *(const bf16x8*)&Kl[slot * 8];
            }
        }
        f32x4 s4 = {0.f, 0.f, 0.f, 0.f};
        #pragma unroll
        for (int kt = 0; kt < 4; ++kt) s4 = __builtin_amdgcn_mfma_f32_16x16x32_bf16(Qh[kt], kbh[kt], s4, 0, 0, 0);
        #pragma unroll
        for (int kt = 0; kt < 4; ++kt) s4 = __builtin_amdgcn_mfma_f32_16x16x32_bf16(Ql[kt], kbh[kt], s4, 0, 0, 0);
        #pragma unroll
        for (int kt = 0; kt < 4; ++kt) s4 = __builtin_amdgcn_mfma_f32_16x16x32_bf16(Qh[kt], kbl[kt], s4, 0, 0, 0);

        #pragma unroll
        for (int reg = 0; reg < 4; ++reg) {    // per-lane online (m,l) only
            float s = s4[reg];
            float mn = fmaxf(m_run[reg], s);
            l_run[reg] = l_run[reg] * __expf(m_run[reg] - mn) + __expf(s - mn);
            m_run[reg] = mn;
        }
    }
    // butterfly merge over the 16 col-lanes
    #pragma unroll
    for (int st = 1; st < 16; st <<= 1) {
        #pragma unroll
        for (int reg = 0; reg < 4; ++reg) {
            float mo = __shfl_xor(m_run[reg], st);
            float lo = __shfl_xor(l_run[reg], st);
            float mn = fmaxf(m_run[reg], mo);
            l_run[reg] = l_run[reg] * __expf(m_run[reg] - mn) + lo * __expf(mo - mn);
            m_run[reg] = mn;
        }
    }
    if (l15 == 0) {
        #pragma unroll
        for (int reg = 0; reg < 4; ++reg) {
            sm_[ct][rt * 16 + g * 4 + reg] = m_run[reg];
            sl_[ct][rt * 16 + g * 4 + reg] = l_run[reg];
        }
    }
    __syncthreads();
    if (t < 32) {
        float M = fmaxf(sm_[0][t], sm_[1][t]);
        float l = sl_[0][t] * __expf(sm_[0][t] - M) + sl_[1][t] * __expf(sm_[1][t] - M);
        pm[blockIdx.x * 8192 + i0 + t] = M;
        pl[blockIdx.x * 8192 + i0 + t] = l;
    }
}

__global__ __launch_bounds__(256) void merge_stats(const float* __restrict__ pm,
                                                   const float* __restrict__ pl,
                                                   float* __restrict__ Mrow,
                                                   float* __restrict__ Rl) {
    int i = blockIdx.x * 256 + threadIdx.x;
    float M = pm[i];
    #pragma unroll
    for (int js = 1; js < 8; ++js) M = fmaxf(M, pm[js * 8192 + i]);
    float l = 0.f;
    #pragma unroll
    for (int js = 0; js < 8; ++js) l += pl[js * 8192 + i] * __expf(pm[js * 8192 + i] - M);
    Mrow[i] = M;
    Rl[i] = 1.0f / l;
}

// ---------------------------------------------------------------------------
// pass2: O_partial = exp(S-M)/l @ V, transposed PV.
// R10: SINGLE-BARRIER software pipeline. R9's mid-iter P-barrier also drained
// vmcnt(0), giving the prefetch only the S-phase (~500cyc) to land. Now each
// tile gets exactly one barrier: iter jt = [barrier; prefetch(jt+1);
// PV(jt-1); S(jt)], so prefetch has a FULL iteration of slack before its
// consumer barrier. Liveness forces triple buffers (at iter jt: Vt[jt-1]
// read, Vt[jt] held, Vt[jt+1] written) -> K/Vt/P x3, rotated by 3x-unrolled
// loop with literal indices (static addressing). LDS 159 KB (<160 KB/WG,
// R9 proved >64KB static launches). Accumulation order over jt unchanged ->
// numerics identical to R9.
// ---------------------------------------------------------------------------
__global__ __launch_bounds__(256, 1) void pass2(const ush* __restrict__ qhg,
                                                const ush* __restrict__ qlg,
                                                const ush* __restrict__ khg,
                                                const ush* __restrict__ klg,
                                                const ush* __restrict__ vtg,
                                                const float* __restrict__ Mrow,
                                                const float* __restrict__ Rl,
                                                ush* __restrict__ part0,
                                                ush* __restrict__ part1) {
    __shared__ __align__(16) ush KhB[3][32 * 128];   // 3 x 8 KB
    __shared__ __align__(16) ush KlB[3][32 * 128];   // 3 x 8 KB
    __shared__ __align__(16) ush VtB[3][512 * 32];   // 3 x 32 KB
    __shared__ __align__(16) ush PB[3][64 * 40];     // 3 x 5 KB

    const int t = threadIdx.x;
    const int lane = t & 63, w = t >> 6;
    const int l15 = lane & 15, g = lane >> 4;
    const int b = blockIdx.x;
    const int xcd = b & 7, lid = b >> 3;
    const int jhalf = xcd >> 2;                  // XCDs 0-3 -> half 0, 4-7 -> half 1
    const int strip = (xcd & 3) * 32 + lid;      // 0..127
    const int i0 = strip * 64;
    const int jbase = jhalf * 4096;

    bf16x8 Qh[2][4], Ql[2][4];
    #pragma unroll
    for (int rt = 0; rt < 2; ++rt) {
        int qrow = i0 + 32 * (w & 1) + rt * 16 + l15;
        #pragma unroll
        for (int kt = 0; kt < 4; ++kt) {
            Qh[rt][kt] = *(const bf16x8*)&qhg[qrow * 128 + kt * 32 + g * 8];
            Ql[rt][kt] = *(const bf16x8*)&qlg[qrow * 128 + kt * 32 + g * 8];
        }
    }
    float Mv[2][4], Rv[2][4];
    #pragma unroll
    for (int rt = 0; rt < 2; ++rt)
        #pragma unroll
        for (int reg = 0; reg < 4; ++reg) {
            int row = i0 + 32 * (w & 1) + rt * 16 + g * 4 + reg;
            Mv[rt][reg] = Mrow[row];
            Rv[rt][reg] = Rl[row];
        }

    f32x4 acc[8][4];
    #pragma unroll
    for (int mt = 0; mt < 8; ++mt)
        #pragma unroll
        for (int nt = 0; nt < 4; ++nt)
            acc[mt][nt] = (f32x4){0.f, 0.f, 0.f, 0.f};

    // async stage one 32-key tile into a buffer set (LDS dst: uniform+lane*16)
    auto stage = [&](ush* KhD, ush* KlD, ush* VtD, int j0) {
        #pragma unroll
        for (int u = 0; u < 2; ++u) {
            int s = u * 256 + t;
            int n = s >> 4, gl = (s & 15) ^ (n & 15);
            int src = (j0 + n) * 128 + gl * 8;
            cp16(&khg[src], &KhD[s * 8]);
            cp16(&klg[src], &KlD[s * 8]);
        }
        #pragma unroll
        for (int u = 0; u < 8; ++u) {
            int s = u * 256 + t;
            int c = s >> 2, gl = (s & 3) ^ ((c >> 1) & 3);
            cp16(&vtg[c * 8192 + j0 + gl * 8], &VtD[s * 8]);
        }
    };

    // S-phase: S=QK^T from K set -> exp -> write P set
    auto s_phase = [&](const ush* KhC, const ush* KlC, ush* Pd) {
        bf16x8 kbh[4], kbl[4];
        {
            int n = (w >> 1) * 16 + l15;
            #pragma unroll
            for (int kt = 0; kt < 4; ++kt) {
                int slot = n * 16 + ((kt * 4 + g) ^ (n & 15));
                kbh[kt] = *(const bf16x8*)&KhC[slot * 8];
                kbl[kt] = *(const bf16x8*)&KlC[slot * 8];
            }
        }
        #pragma unroll
        for (int rt = 0; rt < 2; ++rt) {
            f32x4 s4 = {0.f, 0.f, 0.f, 0.f};
            #pragma unroll
            for (int kt = 0; kt < 4; ++kt) s4 = __builtin_amdgcn_mfma_f32_16x16x32_bf16(Qh[rt][kt], kbh[kt], s4, 0, 0, 0);
            #pragma unroll
            for (int kt = 0; kt < 4; ++kt) s4 = __builtin_amdgcn_mfma_f32_16x16x32_bf16(Ql[rt][kt], kbh[kt], s4, 0, 0, 0);
            #pragma unroll
            for (int kt = 0; kt < 4; ++kt) s4 = __builtin_amdgcn_mfma_f32_16x16x32_bf16(Qh[rt][kt], kbl[kt], s4, 0, 0, 0);
            #pragma unroll
            for (int reg = 0; reg < 4; ++reg) {
                float p = __expf(s4[reg] - Mv[rt][reg]) * Rv[rt][reg];
                int row = 32 * (w & 1) + rt * 16 + g * 4 + reg;
                int col = (w >> 1) * 16 + l15;
                Pd[row * 40 + col] = f2bf(p);
            }
        }
    };

    // PV-phase: O^T += Vt set * P set^T
    auto pv_phase = [&](const ush* Pp, const ush* VtC) {
        bf16x8 Pb[4];
        #pragma unroll
        for (int nt = 0; nt < 4; ++nt)
            Pb[nt] = *(const bf16x8*)&Pp[(nt * 16 + l15) * 40 + g * 8];
        #pragma unroll
        for (int mt = 0; mt < 8; ++mt) {
            int c = w * 128 + mt * 16 + l15;
            int slot = c * 4 + (g ^ ((c >> 1) & 3));
            bf16x8 vf = *(const bf16x8*)&VtC[slot * 8];
            #pragma unroll
            for (int nt = 0; nt < 4; ++nt)
                acc[mt][nt] = __builtin_amdgcn_mfma_f32_16x16x32_bf16(vf, Pb[nt], acc[mt][nt], 0, 0, 0);
        }
    };

    // ---- pipeline ----
    stage(KhB[0], KlB[0], VtB[0], jbase);            // tile 0
    __syncthreads();                                  // drain tile 0
    stage(KhB[1], KlB[1], VtB[1], jbase + 32);       // prefetch tile 1
    s_phase(KhB[0], KlB[0], PB[0]);                  // S tile 0

    int jt = 1;
#define PITER(CUR, PREV, NEXT)                                                  \
    {                                                                           \
        __syncthreads();  /* P[jt-1] visible; K/Vt[jt] drained */               \
        if (jt < 127) stage(KhB[NEXT], KlB[NEXT], VtB[NEXT], jbase + (jt + 1) * 32); \
        pv_phase(PB[PREV], VtB[PREV]);   /* PV tile jt-1 */                     \
        s_phase(KhB[CUR], KlB[CUR], PB[CUR]);  /* S tile jt */                  \
        ++jt;                                                                   \
    }

    for (int g3 = 0; g3 < 42; ++g3) {                // jt = 1..126
        PITER(1, 0, 2)
        PITER(2, 1, 0)
        PITER(0, 2, 1)
    }
    PITER(1, 0, 2)                                   // jt = 127 (no prefetch)
#undef PITER
    __syncthreads();                                  // P[127] visible
    pv_phase(PB[1], VtB[1]);                          // PV tile 127

    ush* prt = (jhalf == 0) ? part0 : part1;
    #pragma unroll
    for (int mt = 0; mt < 8; ++mt)
        #pragma unroll
        for (int nt = 0; nt < 4; ++nt) {
            int qrow = i0 + nt * 16 + l15;
            int vcol = w * 128 + mt * 16 + g * 4;
            uint2 pk;
            pk.x = (unsigned)f2bf(acc[mt][nt][0]) | ((unsigned)f2bf(acc[mt][nt][1]) << 16);
            pk.y = (unsigned)f2bf(acc[mt][nt][2]) | ((unsigned)f2bf(acc[mt][nt][3]) << 16);
            *(uint2*)&prt[qrow * 512 + vcol] = pk;
        }
}

// ---------------------------------------------------------------------------
// merge_k — out += 0.5 * (part0 + part1)
// ---------------------------------------------------------------------------
__global__ __launch_bounds__(256) void merge_k(const ush* __restrict__ p0,
                                               const ush* __restrict__ p1,
                                               float* __restrict__ out) {
    int base = (blockIdx.x * 256 + threadIdx.x) * 8;
    uint4 a = *(const uint4*)&p0[base];
    uint4 b = *(const uint4*)&p1[base];
    float4 o0 = *(float4*)&out[base];
    float4 o1 = *(float4*)&out[base + 4];
    unsigned av[4] = {a.x, a.y, a.z, a.w};
    unsigned bv[4] = {b.x, b.y, b.z, b.w};
    float r[8];
    #pragma unroll
    for (int i = 0; i < 4; ++i) {
        r[2 * i + 0] = 0.5f * (bf2f((ush)(av[i] & 0xFFFF)) + bf2f((ush)(bv[i] & 0xFFFF)));
        r[2 * i + 1] = 0.5f * (bf2f((ush)(av[i] >> 16)) + bf2f((ush)(bv[i] >> 16)));
    }
    o0.x += r[0]; o0.y += r[1]; o0.z += r[2]; o0.w += r[3];
    o1.x += r[4]; o1.y += r[5]; o1.z += r[6]; o1.w += r[7];
    *(float4*)&out[base] = o0;
    *(float4*)&out[base + 4] = o1;
}

// ---------------------------------------------------------------------------
extern "C" void kernel_launch(void* const* d_in, const int* in_sizes, int n_in,
                              void* d_out, int out_size, void* d_ws, size_t ws_size,
                              hipStream_t stream) {
    const float* x  = (const float*)d_in[0];
    const float* W0 = (const float*)d_in[1];
    const float* W1 = (const float*)d_in[2];
    const float* wm = (const float*)d_in[3];
    const float* wt = (const float*)d_in[4];
    float* out = (float*)d_out;
    float* ws  = (float*)d_ws;

    // Region A
    ush* vtg = (ush*)(ws + 0);
    // Region B: xt bf16, then stats overlay after time path
    ush* xtb  = (ush*)(ws + 2097152);
    float* Mr = ws + 2097152;
    float* Rl = ws + 2105344;
    float* pm = ws + 2113536;
    float* pl = ws + 2179072;
    // Region C: weights (early) -> partials (late)
    ush* W01h = (ush*)(ws + 4194304);
    ush* W01l = (ush*)(ws + 4259840);
    ush* wmTh = (ush*)(ws + 4325376);
    ush* wmTl = (ush*)(ws + 4456448);
    ush* wtTh = (ush*)(ws + 4587520);
    ush* wtTl = (ush*)(ws + 4718592);
    ush* part0 = (ush*)(ws + 4194304);
    ush* part1 = (ush*)(ws + 6291456);
    // Region D
    ush* qh = (ush*)(ws + 8388608);
    ush* ql = (ush*)(ws + 8912896);
    ush* kh = (ush*)(ws + 9437184);
    ush* kl = (ush*)(ws + 9961472);
    // Region E
    float* pP = ws + 10485760;
    float* pQ = ws + 10518528;
    float* Ad = ws + 10551296;
    float* Qt = ws + 10551808;

    cast_w01   <<<dim3(64),       256, 0, stream>>>(W0, W1, W01h, W01l);
    cast_wT    <<<dim3(8, 8, 2),  256, 0, stream>>>(wm, wt, wmTh, wmTl, wtTh, wtTl);
    gemm_xv    <<<dim3(4, 64, 2), 256, 0, stream>>>(x, wmTh, wmTl, wtTh, wtTl, vtg, xtb);
    gemm_qk    <<<dim3(2, 128),   256, 0, stream>>>(x, W01h, W01l, qh, ql, kh, kl);
    time_part1 <<<dim3(2, 64),    256, 0, stream>>>(xtb, pP, pQ);
    time_part2 <<<dim3(1),        512, 0, stream>>>(pP, pQ, Ad, Qt);
    time_part3 <<<dim3(2, 64),    256, 0, stream>>>(xtb, pP, pQ, Ad, Qt, out);
    pass1      <<<dim3(8, 256),   256, 0, stream>>>(qh, ql, kh, kl, pm, pl);
    merge_stats<<<dim3(32),       256, 0, stream>>>(pm, pl, Mr, Rl);
    pass2      <<<dim3(256),      256, 0, stream>>>(qh, ql, kh, kl, vtg, Mr, Rl, part0, part1);
    merge_k    <<<dim3(2048),     256, 0, stream>>>(part0, part1, out);
}

// Round 11
// 415.410 us; speedup vs baseline: 1.6007x; 1.0333x over previous
//
#include <hip/hip_runtime.h>
#include <math.h>

// Problem constants
#define NN 8192
#define INS 512
#define FEAT 128

typedef unsigned short ush;
typedef short bf16x8 __attribute__((ext_vector_type(8)));
typedef float f32x4 __attribute__((ext_vector_type(4)));

__device__ __forceinline__ ush f2bf(float f) {           // RNE fp32->bf16
    unsigned u = __float_as_uint(f);
    unsigned r = (u + 0x7FFFu + ((u >> 16) & 1u)) >> 16;
    return (ush)r;
}
__device__ __forceinline__ float bf2f(ush h) {
    return __uint_as_float(((unsigned)h) << 16);
}
// async 16B global -> LDS (gfx950 global_load_lds_dwordx4). LDS dst must be
// wave-uniform-base + lane*16 — our staging layouts satisfy this by design.
__device__ __forceinline__ void cp16(const ush* g, ush* l) {
    __builtin_amdgcn_global_load_lds(
        (const __attribute__((address_space(1))) void*)g,
        (__attribute__((address_space(3))) void*)l, 16, 0, 0);
}
// trunc-split 8 floats into hi bf16 (truncation) + lo bf16 (RNE of residual).
__device__ __forceinline__ void split8(float4 f0, float4 f1, uint4& h, uint4& l) {
    float f[8] = {f0.x, f0.y, f0.z, f0.w, f1.x, f1.y, f1.z, f1.w};
    unsigned hu[8], lu[8];
    #pragma unroll
    for (int j = 0; j < 8; ++j) {
        unsigned u = __float_as_uint(f[j]);
        hu[j] = u >> 16;
        float lo = f[j] - __uint_as_float(u & 0xFFFF0000u);
        lu[j] = (unsigned)f2bf(lo);
    }
    h.x = hu[0] | (hu[1] << 16); h.y = hu[2] | (hu[3] << 16);
    h.z = hu[4] | (hu[5] << 16); h.w = hu[6] | (hu[7] << 16);
    l.x = lu[0] | (lu[1] << 16); l.y = lu[2] | (lu[3] << 16);
    l.z = lu[4] | (lu[5] << 16); l.w = lu[6] | (lu[7] << 16);
}

// ws layout (float offsets), total = 10,552,320 floats = 42.2 MB.
//  A [0,2097152)        : vtg bf16 [512][8192]
//  B [2097152,4194304)  : xt bf16 -> (after time path) Mrow/Rl/pm/pl
//  C [4194304,8388608)  : weights hi/lo (early) -> part0/part1 bf16 (pass2)
//  D [8388608,10485760) : qh,ql,kh,kl bf16 [8192][128]
//  E [10485760,10552320): pP,pQ,Ad,Qt fp32

// ---------------------------------------------------------------------------
// cast_w01: W0,W1 [128][512] fp32 -> W01h/W01l [256][512] bf16
// ---------------------------------------------------------------------------
__global__ __launch_bounds__(256) void cast_w01(const float* __restrict__ W0,
                                                const float* __restrict__ W1,
                                                ush* __restrict__ W01h,
                                                ush* __restrict__ W01l) {
    int idx = (blockIdx.x * 256 + threadIdx.x) * 8;      // 131072 elements total
    int r = idx >> 9, c = idx & 511;
    const float* src = (r < 128) ? &W0[r * 512 + c] : &W1[(r - 128) * 512 + c];
    float4 f0 = *(const float4*)src;
    float4 f1 = *(const float4*)(src + 4);
    uint4 h, l;
    split8(f0, f1, h, l);
    *(uint4*)&W01h[idx] = h;
    *(uint4*)&W01l[idx] = l;
}

// ---------------------------------------------------------------------------
// cast_wT: wm/wt [512k][512n] fp32 -> transposed hi/lo bf16 [512n][512k]
// ---------------------------------------------------------------------------
__global__ __launch_bounds__(256) void cast_wT(const float* __restrict__ wm,
                                               const float* __restrict__ wt,
                                               ush* __restrict__ wmTh, ush* __restrict__ wmTl,
                                               ush* __restrict__ wtTh, ush* __restrict__ wtTl) {
    const float* src = blockIdx.z ? wt : wm;
    ush* oh = blockIdx.z ? wtTh : wmTh;
    ush* ol = blockIdx.z ? wtTl : wmTl;
    __shared__ float T[64][65];
    const int t = threadIdx.x;
    const int k0 = blockIdx.y * 64, n0 = blockIdx.x * 64;
    #pragma unroll
    for (int u = 0; u < 4; ++u) {
        int idx = u * 256 + t;
        int r = idx >> 4, c4 = (idx & 15) * 4;
        *(float4*)&T[r][c4] = *(const float4*)&src[(k0 + r) * 512 + n0 + c4];
    }
    __syncthreads();
    #pragma unroll
    for (int u = 0; u < 4; ++u) {
        int idx = u * 256 + t;
        int a = idx >> 4, b4 = (idx & 15) * 4;   // out row n0+a, k cols k0+b4..+3
        unsigned hu[4], lu[4];
        #pragma unroll
        for (int j = 0; j < 4; ++j) {
            float f = T[b4 + j][a];
            unsigned uu = __float_as_uint(f);
            hu[j] = uu >> 16;
            lu[j] = (unsigned)f2bf(f - __uint_as_float(uu & 0xFFFF0000u));
        }
        uint2 hp, lp;
        hp.x = hu[0] | (hu[1] << 16); hp.y = hu[2] | (hu[3] << 16);
        lp.x = lu[0] | (lu[1] << 16); lp.y = lu[2] | (lu[3] << 16);
        *(uint2*)&oh[(n0 + a) * 512 + k0 + b4] = hp;
        *(uint2*)&ol[(n0 + a) * 512 + k0 + b4] = lp;
    }
}

// ---------------------------------------------------------------------------
// gemm_xv: C = x @ w (hi/lo bf16 MFMA, 3 terms), 128x128 tile, BK=32.
// z=0: w=weight, writes vtg TRANSPOSED (bf16). z=1: w=weight_time, writes xt.
// ---------------------------------------------------------------------------
__global__ __launch_bounds__(256) void gemm_xv(const float* __restrict__ x,
    const ush* __restrict__ wmTh, const ush* __restrict__ wmTl,
    const ush* __restrict__ wtTh, const ush* __restrict__ wtTl,
    ush* __restrict__ vtg, ush* __restrict__ xtb) {
    const bool isV = (blockIdx.z == 0);
    const ush* Bhg = isV ? wmTh : wtTh;
    const ush* Blg = isV ? wmTl : wtTl;
    __shared__ __align__(16) ush sm[20480];   // 40 KB; reused as LT in epilogue
    ush* Ah = sm;
    ush* Al = sm + 5120;
    ush* Bh = sm + 10240;
    ush* Bl = sm + 15360;
    const int t = threadIdx.x;
    const int lane = t & 63, w = t >> 6;
    const int l15 = lane & 15, g4 = lane >> 4;
    const int m0 = blockIdx.y * 128, n0 = blockIdx.x * 128;
    const int wm0 = (w & 1) * 64, wn0 = (w >> 1) * 64;
    f32x4 acc[4][4];
    #pragma unroll
    for (int mt = 0; mt < 4; ++mt)
        #pragma unroll
        for (int nt = 0; nt < 4; ++nt)
            acc[mt][nt] = (f32x4){0.f, 0.f, 0.f, 0.f};

    const int am = t >> 1, akh = (t & 1) * 16;
    for (int k0 = 0; k0 < 512; k0 += 32) {
        __syncthreads();
        {   // stage A (x fp32 -> hi/lo bf16 granules)
            const float* src = &x[(m0 + am) * 512 + k0 + akh];
            float4 f0 = *(const float4*)&src[0];
            float4 f1 = *(const float4*)&src[4];
            float4 f2 = *(const float4*)&src[8];
            float4 f3 = *(const float4*)&src[12];
            uint4 h0, l0, h1, l1;
            split8(f0, f1, h0, l0);
            split8(f2, f3, h1, l1);
            int s0 = am * 5 + (akh >> 3);
            *(uint4*)&Ah[s0 * 8] = h0; *(uint4*)&Ah[(s0 + 1) * 8] = h1;
            *(uint4*)&Al[s0 * 8] = l0; *(uint4*)&Al[(s0 + 1) * 8] = l1;
        }
        #pragma unroll
        for (int u = 0; u < 2; ++u) {   // stage B (pre-split bf16)
            int s = u * 256 + t;
            int n = s >> 2, g = s & 3;
            int srco = (n0 + n) * 512 + k0 + g * 8;
            int slot = n * 5 + g;
            *(uint4*)&Bh[slot * 8] = *(const uint4*)&Bhg[srco];
            *(uint4*)&Bl[slot * 8] = *(const uint4*)&Blg[srco];
        }
        __syncthreads();
        bf16x8 ah[4], al[4], bh[4], bl[4];
        #pragma unroll
        for (int mt = 0; mt < 4; ++mt) {
            int slot = (wm0 + mt * 16 + l15) * 5 + g4;
            ah[mt] = *(const bf16x8*)&Ah[slot * 8];
            al[mt] = *(const bf16x8*)&Al[slot * 8];
        }
        #pragma unroll
        for (int nt = 0; nt < 4; ++nt) {
            int slot = (wn0 + nt * 16 + l15) * 5 + g4;
            bh[nt] = *(const bf16x8*)&Bh[slot * 8];
            bl[nt] = *(const bf16x8*)&Bl[slot * 8];
        }
        #pragma unroll
        for (int mt = 0; mt < 4; ++mt)
            #pragma unroll
            for (int nt = 0; nt < 4; ++nt) {
                acc[mt][nt] = __builtin_amdgcn_mfma_f32_16x16x32_bf16(ah[mt], bh[nt], acc[mt][nt], 0, 0, 0);
                acc[mt][nt] = __builtin_amdgcn_mfma_f32_16x16x32_bf16(al[mt], bh[nt], acc[mt][nt], 0, 0, 0);
                acc[mt][nt] = __builtin_amdgcn_mfma_f32_16x16x32_bf16(ah[mt], bl[nt], acc[mt][nt], 0, 0, 0);
            }
    }

    if (!isV) {   // xt: direct bf16 stores
        #pragma unroll
        for (int mt = 0; mt < 4; ++mt)
            #pragma unroll
            for (int nt = 0; nt < 4; ++nt) {
                int col = n0 + wn0 + nt * 16 + l15;
                int rowb = m0 + wm0 + mt * 16 + g4 * 4;
                #pragma unroll
                for (int reg = 0; reg < 4; ++reg)
                    xtb[(rowb + reg) * 512 + col] = f2bf(acc[mt][nt][reg]);
            }
    } else {      // vtg: transpose through LDS
        __syncthreads();
        #pragma unroll
        for (int mt = 0; mt < 4; ++mt)
            #pragma unroll
            for (int nt = 0; nt < 4; ++nt) {
                int nl = wn0 + nt * 16 + l15;
                int mb = wm0 + mt * 16 + g4 * 4;
                uint2 pk;
                pk.x = (unsigned)f2bf(acc[mt][nt][0]) | ((unsigned)f2bf(acc[mt][nt][1]) << 16);
                pk.y = (unsigned)f2bf(acc[mt][nt][2]) | ((unsigned)f2bf(acc[mt][nt][3]) << 16);
                *(uint2*)&sm[nl * 136 + mb] = pk;
            }
        __syncthreads();
        int a = t >> 1, off = (t & 1) * 64;
        #pragma unroll
        for (int u = 0; u < 8; ++u)
            *(uint4*)&vtg[(n0 + a) * 8192 + m0 + off + u * 8] =
                *(const uint4*)&sm[a * 136 + off + u * 8];
    }
}

// ---------------------------------------------------------------------------
// gemm_qk: [q|k] = x @ [W0|W1]^T (hi/lo MFMA) -> qh/ql/kh/kl
// BM=64, BN=128 -> grid (2,128) = 256 blocks.
// ---------------------------------------------------------------------------
__global__ __launch_bounds__(256) void gemm_qk(const float* __restrict__ x,
    const ush* __restrict__ W01h, const ush* __restrict__ W01l,
    ush* __restrict__ qh, ush* __restrict__ ql,
    ush* __restrict__ kh, ush* __restrict__ kl) {
    __shared__ __align__(16) ush sm[15360];   // Ah 2560 | Al 2560 | Bh 5120 | Bl 5120
    ush* Ah = sm;
    ush* Al = sm + 2560;
    ush* Bh = sm + 5120;
    ush* Bl = sm + 10240;
    const int t = threadIdx.x;
    const int lane = t & 63, w = t >> 6;
    const int l15 = lane & 15, g4 = lane >> 4;
    const int m0 = blockIdx.y * 64, n0 = blockIdx.x * 128;
    const int wm0 = (w & 1) * 32, wn0 = (w >> 1) * 64;
    f32x4 acc[2][4];
    #pragma unroll
    for (int mt = 0; mt < 2; ++mt)
        #pragma unroll
        for (int nt = 0; nt < 4; ++nt)
            acc[mt][nt] = (f32x4){0.f, 0.f, 0.f, 0.f};

    const int ar = t >> 2, ag = t & 3;       // A: row ar, k-granule ag
    for (int k0 = 0; k0 < 512; k0 += 32) {
        __syncthreads();
        {   // stage A (64 rows x 32 k, split on the fly)
            const float* src = &x[(m0 + ar) * 512 + k0 + ag * 8];
            float4 f0 = *(const float4*)&src[0];
            float4 f1 = *(const float4*)&src[4];
            uint4 h, l;
            split8(f0, f1, h, l);
            int slot = ar * 5 + ag;
            *(uint4*)&Ah[slot * 8] = h;
            *(uint4*)&Al[slot * 8] = l;
        }
        #pragma unroll
        for (int u = 0; u < 2; ++u) {        // stage B (128 n x 32 k, pre-split)
            int s = u * 256 + t;
            int n = s >> 2, g = s & 3;
            int srco = (n0 + n) * 512 + k0 + g * 8;
            int slot = n * 5 + g;
            *(uint4*)&Bh[slot * 8] = *(const uint4*)&W01h[srco];
            *(uint4*)&Bl[slot * 8] = *(const uint4*)&W01l[srco];
        }
        __syncthreads();
        bf16x8 ah[2], al[2], bh[4], bl[4];
        #pragma unroll
        for (int mt = 0; mt < 2; ++mt) {
            int slot = (wm0 + mt * 16 + l15) * 5 + g4;
            ah[mt] = *(const bf16x8*)&Ah[slot * 8];
            al[mt] = *(const bf16x8*)&Al[slot * 8];
        }
        #pragma unroll
        for (int nt = 0; nt < 4; ++nt) {
            int slot = (wn0 + nt * 16 + l15) * 5 + g4;
            bh[nt] = *(const bf16x8*)&Bh[slot * 8];
            bl[nt] = *(const bf16x8*)&Bl[slot * 8];
        }
        #pragma unroll
        for (int mt = 0; mt < 2; ++mt)
            #pragma unroll
            for (int nt = 0; nt < 4; ++nt) {
                acc[mt][nt] = __builtin_amdgcn_mfma_f32_16x16x32_bf16(ah[mt], bh[nt], acc[mt][nt], 0, 0, 0);
                acc[mt][nt] = __builtin_amdgcn_mfma_f32_16x16x32_bf16(al[mt], bh[nt], acc[mt][nt], 0, 0, 0);
                acc[mt][nt] = __builtin_amdgcn_mfma_f32_16x16x32_bf16(ah[mt], bl[nt], acc[mt][nt], 0, 0, 0);
            }
    }
    ush* oh = (n0 == 0) ? qh : kh;
    ush* ol = (n0 == 0) ? ql : kl;
    #pragma unroll
    for (int mt = 0; mt < 2; ++mt)
        #pragma unroll
        for (int nt = 0; nt < 4; ++nt) {
            int col = wn0 + nt * 16 + l15;
            int rowb = m0 + wm0 + mt * 16 + g4 * 4;
            #pragma unroll
            for (int reg = 0; reg < 4; ++reg) {
                float v = acc[mt][nt][reg];
                unsigned u = __float_as_uint(v);
                ush h = (ush)(u >> 16);
                ush lo = f2bf(v - __uint_as_float(u & 0xFFFF0000u));
                oh[(rowb + reg) * 128 + col] = h;
                ol[(rowb + reg) * 128 + col] = lo;
            }
        }
}

// ---------------------------------------------------------------------------
// time path (xt bf16)
// ---------------------------------------------------------------------------
__global__ __launch_bounds__(256) void time_part1(const ush* __restrict__ xtb,
                                                  float* __restrict__ pP,
                                                  float* __restrict__ pQ) {
    int d = blockIdx.x * 256 + threadIdx.x;
    int r0 = blockIdx.y * 128;
    float sp = 0.f, sq = 0.f;
    for (int r = 0; r < 128; ++r) {
        float v = bf2f(xtb[(r0 + r) * 512 + d]);
        sp += v;
        sq += (float)(r0 + r) * v;
    }
    pP[blockIdx.y * 512 + d] = sp;
    pQ[blockIdx.y * 512 + d] = sq;
}

__global__ __launch_bounds__(512) void time_part2(float* __restrict__ pP,
                                                  float* __restrict__ pQ,
                                                  float* __restrict__ Ad,
                                                  float* __restrict__ Qt) {
    int d = threadIdx.x;
    float rp = 0.f, rq = 0.f;
    for (int c = 0; c < 64; ++c) {
        int idx = c * 512 + d;
        float p = pP[idx], qv = pQ[idx];
        pP[idx] = rp; pQ[idx] = rq;
        rp += p; rq += qv;
    }
    Ad[d] = rp; Qt[d] = rq;
}

__global__ __launch_bounds__(256) void time_part3(const ush* __restrict__ xtb,
                                                  const float* __restrict__ pP,
                                                  const float* __restrict__ pQ,
                                                  const float* __restrict__ Ad,
                                                  const float* __restrict__ Qt,
                                                  float* __restrict__ out) {
    int d = blockIdx.x * 256 + threadIdx.x;
    int r0 = blockIdx.y * 128;
    float P = pP[blockIdx.y * 512 + d];
    float Q = pQ[blockIdx.y * 512 + d];
    float A = Ad[d], Qtot = Qt[d];
    for (int r = 0; r < 128; ++r) {
        int i = r0 + r;
        float v = bf2f(xtb[i * 512 + d]);
        P += v;
        float fi = (float)i;
        Q += fi * v;
        float B = 2.f * fi * P - 2.f * Q + Qtot - fi * A;
        int Si = 67108864 - (i * (i + 1)) / 2 - ((8191 - i) * (8192 - i)) / 2;
        float T = (8192.f * A - B) / (float)Si;
        out[i * 512 + d] = 0.5f * T;
    }
}

// ---------------------------------------------------------------------------
// pass1: softmax stats. R11: BM 32->128 (4 rowtiles/wave) — each staged K
// tile now serves 128 Q-rows (4x staging amortization; staged bytes
// 1.07 GB -> 268 MB, the inferred ~110 us was K-supply-bound). 1D grid 512
// with XCD mapping: jchunk = b&7 -> all 64 blocks of an XCD stream the same
// 2 MB K-chunk (L2-resident). Per-element S-chain order unchanged ->
// bitwise-identical M/l to pass2's chain.
// ---------------------------------------------------------------------------
__global__ __launch_bounds__(256, 2) void pass1(const ush* __restrict__ qhg,
                                                const ush* __restrict__ qlg,
                                                const ush* __restrict__ khg,
                                                const ush* __restrict__ klg,
                                                float* __restrict__ pm,
                                                float* __restrict__ pl) {
    __shared__ __align__(16) ush Kh[32 * 128];
    __shared__ __align__(16) ush Kl[32 * 128];
    __shared__ float sm_[2][128], sl_[2][128];
    const int t = threadIdx.x;
    const int lane = t & 63, w = t >> 6;
    const int rt0 = w & 1, ct = w >> 1;
    const int b = blockIdx.x;
    const int jc = b & 7, ib = b >> 3;           // XCD shares jchunk
    const int i0 = ib * 128;
    const int jbase = jc * 1024;
    const int l15 = lane & 15, g = lane >> 4;

    bf16x8 Qh[4][4], Ql[4][4];                   // [rr][kt], rows (rt0+2rr)*16+l15
    #pragma unroll
    for (int rr = 0; rr < 4; ++rr) {
        int qrow = i0 + (rt0 + 2 * rr) * 16 + l15;
        #pragma unroll
        for (int kt = 0; kt < 4; ++kt) {
            Qh[rr][kt] = *(const bf16x8*)&qhg[qrow * 128 + kt * 32 + g * 8];
            Ql[rr][kt] = *(const bf16x8*)&qlg[qrow * 128 + kt * 32 + g * 8];
        }
    }
    float m_run[4][4], l_run[4][4];
    #pragma unroll
    for (int rr = 0; rr < 4; ++rr)
        #pragma unroll
        for (int reg = 0; reg < 4; ++reg) { m_run[rr][reg] = -INFINITY; l_run[rr][reg] = 0.f; }

    for (int jt = 0; jt < 32; ++jt) {
        int j0 = jbase + jt * 32;
        __syncthreads();
        #pragma unroll
        for (int u = 0; u < 2; ++u) {
            int s = u * 256 + t;
            int n = s >> 4, gl = (s & 15) ^ (n & 15);
            int src = (j0 + n) * 128 + gl * 8;
            *(uint4*)&Kh[s * 8] = *(const uint4*)&khg[src];
            *(uint4*)&Kl[s * 8] = *(const uint4*)&klg[src];
        }
        __syncthreads();

        bf16x8 kbh[4], kbl[4];
        {
            int n = ct * 16 + l15;
            #pragma unroll
            for (int kt = 0; kt < 4; ++kt) {
                int slot = n * 16 + ((kt * 4 + g) ^ (n & 15));
                kbh[kt] = *(const bf16x8*)&Kh[slot * 8];
                kbl[kt] = *(const bf16x8*)&Kl[slot * 8];
            }
        }
        #pragma unroll
        for (int rr = 0; rr < 4; ++rr) {
            f32x4 s4 = {0.f, 0.f, 0.f, 0.f};
            #pragma unroll
            for (int kt = 0; kt < 4; ++kt) s4 = __builtin_amdgcn_mfma_f32_16x16x32_bf16(Qh[rr][kt], kbh[kt], s4, 0, 0, 0);
            #pragma unroll
            for (int kt = 0; kt < 4; ++kt) s4 = __builtin_amdgcn_mfma_f32_16x16x32_bf16(Ql[rr][kt], kbh[kt], s4, 0, 0, 0);
            #pragma unroll
            for (int kt = 0; kt < 4; ++kt) s4 = __builtin_amdgcn_mfma_f32_16x16x32_bf16(Qh[rr][kt], kbl[kt], s4, 0, 0, 0);
            #pragma unroll
            for (int reg = 0; reg < 4; ++reg) {    // per-lane online (m,l)
                float s = s4[reg];
                float mn = fmaxf(m_run[rr][reg], s);
                l_run[rr][reg] = l_run[rr][reg] * __expf(m_run[rr][reg] - mn) + __expf(s - mn);
                m_run[rr][reg] = mn;
            }
        }
    }
    // butterfly merge over the 16 col-lanes
    #pragma unroll
    for (int st = 1; st < 16; st <<= 1) {
        #pragma unroll
        for (int rr = 0; rr < 4; ++rr)
            #pragma unroll
            for (int reg = 0; reg < 4; ++reg) {
                float mo = __shfl_xor(m_run[rr][reg], st);
                float lo = __shfl_xor(l_run[rr][reg], st);
                float mn = fmaxf(m_run[rr][reg], mo);
                l_run[rr][reg] = l_run[rr][reg] * __expf(m_run[rr][reg] - mn) + lo * __expf(mo - mn);
                m_run[rr][reg] = mn;
            }
    }
    if (l15 == 0) {
        #pragma unroll
        for (int rr = 0; rr < 4; ++rr)
            #pragma unroll
            for (int reg = 0; reg < 4; ++reg) {
                int row = (rt0 + 2 * rr) * 16 + g * 4 + reg;
                sm_[ct][row] = m_run[rr][reg];
                sl_[ct][row] = l_run[rr][reg];
            }
    }
    __syncthreads();
    if (t < 128) {
        float M = fmaxf(sm_[0][t], sm_[1][t]);
        float l = sl_[0][t] * __expf(sm_[0][t] - M) + sl_[1][t] * __expf(sm_[1][t] - M);
        pm[jc * 8192 + i0 + t] = M;
        pl[jc * 8192 + i0 + t] = l;
    }
}

__global__ __launch_bounds__(256) void merge_stats(const float* __restrict__ pm,
                                                   const float* __restrict__ pl,
                                                   float* __restrict__ Mrow,
                                                   float* __restrict__ Rl) {
    int i = blockIdx.x * 256 + threadIdx.x;
    float M = pm[i];
    #pragma unroll
    for (int js = 1; js < 8; ++js) M = fmaxf(M, pm[js * 8192 + i]);
    float l = 0.f;
    #pragma unroll
    for (int js = 0; js < 8; ++js) l += pl[js * 8192 + i] * __expf(pm[js * 8192 + i] - M);
    Mrow[i] = M;
    Rl[i] = 1.0f / l;
}

// ---------------------------------------------------------------------------
// pass2 (R9 exact — best measured at 191 us): double-buffered staging via
// global_load_lds (16B), 2-barrier structure, BM=64, grid 256 XCD-swizzled.
// R10's single-barrier variant measured 202 -> reverted. The vmcnt(0) drain
// before s_barrier is structural; this is the plateau of this K-loop shape.
// ---------------------------------------------------------------------------
__global__ __launch_bounds__(256, 1) void pass2(const ush* __restrict__ qhg,
                                                const ush* __restrict__ qlg,
                                                const ush* __restrict__ khg,
                                                const ush* __restrict__ klg,
                                                const ush* __restrict__ vtg,
                                                const float* __restrict__ Mrow,
                                                const float* __restrict__ Rl,
                                                ush* __restrict__ part0,
                                                ush* __restrict__ part1) {
    __shared__ __align__(16) ush Kh0[32 * 128];   // 8 KB
    __shared__ __align__(16) ush Kl0[32 * 128];   // 8 KB
    __shared__ __align__(16) ush Vt0[512 * 32];   // 32 KB
    __shared__ __align__(16) ush Kh1[32 * 128];   // 8 KB
    __shared__ __align__(16) ush Kl1[32 * 128];   // 8 KB
    __shared__ __align__(16) ush Vt1[512 * 32];   // 32 KB
    __shared__ __align__(16) ush P[64 * 40];      // 5 KB

    const int t = threadIdx.x;
    const int lane = t & 63, w = t >> 6;
    const int l15 = lane & 15, g = lane >> 4;
    const int b = blockIdx.x;
    const int xcd = b & 7, lid = b >> 3;
    const int jhalf = xcd >> 2;                  // XCDs 0-3 -> half 0, 4-7 -> half 1
    const int strip = (xcd & 3) * 32 + lid;      // 0..127
    const int i0 = strip * 64;
    const int jbase = jhalf * 4096;

    bf16x8 Qh[2][4], Ql[2][4];
    #pragma unroll
    for (int rt = 0; rt < 2; ++rt) {
        int qrow = i0 + 32 * (w & 1) + rt * 16 + l15;
        #pragma unroll
        for (int kt = 0; kt < 4; ++kt) {
            Qh[rt][kt] = *(const bf16x8*)&qhg[qrow * 128 + kt * 32 + g * 8];
            Ql[rt][kt] = *(const bf16x8*)&qlg[qrow * 128 + kt * 32 + g * 8];
        }
    }
    float Mv[2][4], Rv[2][4];
    #pragma unroll
    for (int rt = 0; rt < 2; ++rt)
        #pragma unroll
        for (int reg = 0; reg < 4; ++reg) {
            int row = i0 + 32 * (w & 1) + rt * 16 + g * 4 + reg;
            Mv[rt][reg] = Mrow[row];
            Rv[rt][reg] = Rl[row];
        }

    f32x4 acc[8][4];
    #pragma unroll
    for (int mt = 0; mt < 8; ++mt)
        #pragma unroll
        for (int nt = 0; nt < 4; ++nt)
            acc[mt][nt] = (f32x4){0.f, 0.f, 0.f, 0.f};

    // async stage one 32-key tile into a buffer set (LDS dst: uniform+lane*16)
    auto stage = [&](ush* KhD, ush* KlD, ush* VtD, int j0) {
        #pragma unroll
        for (int u = 0; u < 2; ++u) {
            int s = u * 256 + t;
            int n = s >> 4, gl = (s & 15) ^ (n & 15);
            int src = (j0 + n) * 128 + gl * 8;
            cp16(&khg[src], &KhD[s * 8]);
            cp16(&klg[src], &KlD[s * 8]);
        }
        #pragma unroll
        for (int u = 0; u < 8; ++u) {
            int s = u * 256 + t;
            int c = s >> 2, gl = (s & 3) ^ ((c >> 1) & 3);
            cp16(&vtg[c * 8192 + j0 + gl * 8], &VtD[s * 8]);
        }
    };

    // one pipeline iteration: compute from C-set, prefetch into N-set
    auto iter = [&](const ush* KhC, const ush* KlC, const ush* VtC,
                    ush* KhN, ush* KlN, ush* VtN, int jt) {
        __syncthreads();                       // (A) C-set loads complete; prev PV reads done
        if (jt < 127) stage(KhN, KlN, VtN, jbase + (jt + 1) * 32);

        // ---- S = Q K^T ----
        bf16x8 kbh[4], kbl[4];
        {
            int n = (w >> 1) * 16 + l15;
            #pragma unroll
            for (int kt = 0; kt < 4; ++kt) {
                int slot = n * 16 + ((kt * 4 + g) ^ (n & 15));
                kbh[kt] = *(const bf16x8*)&KhC[slot * 8];
                kbl[kt] = *(const bf16x8*)&KlC[slot * 8];
            }
        }
        #pragma unroll
        for (int rt = 0; rt < 2; ++rt) {
            f32x4 s4 = {0.f, 0.f, 0.f, 0.f};
            #pragma unroll
            for (int kt = 0; kt < 4; ++kt) s4 = __builtin_amdgcn_mfma_f32_16x16x32_bf16(Qh[rt][kt], kbh[kt], s4, 0, 0, 0);
            #pragma unroll
            for (int kt = 0; kt < 4; ++kt) s4 = __builtin_amdgcn_mfma_f32_16x16x32_bf16(Ql[rt][kt], kbh[kt], s4, 0, 0, 0);
            #pragma unroll
            for (int kt = 0; kt < 4; ++kt) s4 = __builtin_amdgcn_mfma_f32_16x16x32_bf16(Qh[rt][kt], kbl[kt], s4, 0, 0, 0);
            #pragma unroll
            for (int reg = 0; reg < 4; ++reg) {
                float p = __expf(s4[reg] - Mv[rt][reg]) * Rv[rt][reg];
                int row = 32 * (w & 1) + rt * 16 + g * 4 + reg;
                int col = (w >> 1) * 16 + l15;
                P[row * 40 + col] = f2bf(p);
            }
        }
        __syncthreads();                       // (B) P visible

        // ---- O^T += Vt_tile * P^T ----
        bf16x8 Pb[4];
        #pragma unroll
        for (int nt = 0; nt < 4; ++nt)
            Pb[nt] = *(const bf16x8*)&P[(nt * 16 + l15) * 40 + g * 8];
        #pragma unroll
        for (int mt = 0; mt < 8; ++mt) {
            int c = w * 128 + mt * 16 + l15;
            int slot = c * 4 + (g ^ ((c >> 1) & 3));
            bf16x8 vf = *(const bf16x8*)&VtC[slot * 8];
            #pragma unroll
            for (int nt = 0; nt < 4; ++nt)
                acc[mt][nt] = __builtin_amdgcn_mfma_f32_16x16x32_bf16(vf, Pb[nt], acc[mt][nt], 0, 0, 0);
        }
    };

    stage(Kh0, Kl0, Vt0, jbase);               // prologue: fill set 0
    for (int jj = 0; jj < 64; ++jj) {
        iter(Kh0, Kl0, Vt0, Kh1, Kl1, Vt1, 2 * jj);
        iter(Kh1, Kl1, Vt1, Kh0, Kl0, Vt0, 2 * jj + 1);
    }

    ush* prt = (jhalf == 0) ? part0 : part1;
    #pragma unroll
    for (int mt = 0; mt < 8; ++mt)
        #pragma unroll
        for (int nt = 0; nt < 4; ++nt) {
            int qrow = i0 + nt * 16 + l15;
            int vcol = w * 128 + mt * 16 + g * 4;
            uint2 pk;
            pk.x = (unsigned)f2bf(acc[mt][nt][0]) | ((unsigned)f2bf(acc[mt][nt][1]) << 16);
            pk.y = (unsigned)f2bf(acc[mt][nt][2]) | ((unsigned)f2bf(acc[mt][nt][3]) << 16);
            *(uint2*)&prt[qrow * 512 + vcol] = pk;
        }
}

// ---------------------------------------------------------------------------
// merge_k — out += 0.5 * (part0 + part1)
// ---------------------------------------------------------------------------
__global__ __launch_bounds__(256) void merge_k(const ush* __restrict__ p0,
                                               const ush* __restrict__ p1,
                                               float* __restrict__ out) {
    int base = (blockIdx.x * 256 + threadIdx.x) * 8;
    uint4 a = *(const uint4*)&p0[base];
    uint4 b = *(const uint4*)&p1[base];
    float4 o0 = *(float4*)&out[base];
    float4 o1 = *(float4*)&out[base + 4];
    unsigned av[4] = {a.x, a.y, a.z, a.w};
    unsigned bv[4] = {b.x, b.y, b.z, b.w};
    float r[8];
    #pragma unroll
    for (int i = 0; i < 4; ++i) {
        r[2 * i + 0] = 0.5f * (bf2f((ush)(av[i] & 0xFFFF)) + bf2f((ush)(bv[i] & 0xFFFF)));
        r[2 * i + 1] = 0.5f * (bf2f((ush)(av[i] >> 16)) + bf2f((ush)(bv[i] >> 16)));
    }
    o0.x += r[0]; o0.y += r[1]; o0.z += r[2]; o0.w += r[3];
    o1.x += r[4]; o1.y += r[5]; o1.z += r[6]; o1.w += r[7];
    *(float4*)&out[base] = o0;
    *(float4*)&out[base + 4] = o1;
}

// ---------------------------------------------------------------------------
extern "C" void kernel_launch(void* const* d_in, const int* in_sizes, int n_in,
                              void* d_out, int out_size, void* d_ws, size_t ws_size,
                              hipStream_t stream) {
    const float* x  = (const float*)d_in[0];
    const float* W0 = (const float*)d_in[1];
    const float* W1 = (const float*)d_in[2];
    const float* wm = (const float*)d_in[3];
    const float* wt = (const float*)d_in[4];
    float* out = (float*)d_out;
    float* ws  = (float*)d_ws;

    // Region A
    ush* vtg = (ush*)(ws + 0);
    // Region B: xt bf16, then stats overlay after time path
    ush* xtb  = (ush*)(ws + 2097152);
    float* Mr = ws + 2097152;
    float* Rl = ws + 2105344;
    float* pm = ws + 2113536;
    float* pl = ws + 2179072;
    // Region C: weights (early) -> partials (late)
    ush* W01h = (ush*)(ws + 4194304);
    ush* W01l = (ush*)(ws + 4259840);
    ush* wmTh = (ush*)(ws + 4325376);
    ush* wmTl = (ush*)(ws + 4456448);
    ush* wtTh = (ush*)(ws + 4587520);
    ush* wtTl = (ush*)(ws + 4718592);
    ush* part0 = (ush*)(ws + 4194304);
    ush* part1 = (ush*)(ws + 6291456);
    // Region D
    ush* qh = (ush*)(ws + 8388608);
    ush* ql = (ush*)(ws + 8912896);
    ush* kh = (ush*)(ws + 9437184);
    ush* kl = (ush*)(ws + 9961472);
    // Region E
    float* pP = ws + 10485760;
    float* pQ = ws + 10518528;
    float* Ad = ws + 10551296;
    float* Qt = ws + 10551808;

    cast_w01   <<<dim3(64),       256, 0, stream>>>(W0, W1, W01h, W01l);
    cast_wT    <<<dim3(8, 8, 2),  256, 0, stream>>>(wm, wt, wmTh, wmTl, wtTh, wtTl);
    gemm_xv    <<<dim3(4, 64, 2), 256, 0, stream>>>(x, wmTh, wmTl, wtTh, wtTl, vtg, xtb);
    gemm_qk    <<<dim3(2, 128),   256, 0, stream>>>(x, W01h, W01l, qh, ql, kh, kl);
    time_part1 <<<dim3(2, 64),    256, 0, stream>>>(xtb, pP, pQ);
    time_part2 <<<dim3(1),        512, 0, stream>>>(pP, pQ, Ad, Qt);
    time_part3 <<<dim3(2, 64),    256, 0, stream>>>(xtb, pP, pQ, Ad, Qt, out);
    pass1      <<<dim3(512),      256, 0, stream>>>(qh, ql, kh, kl, pm, pl);
    merge_stats<<<dim3(32),       256, 0, stream>>>(pm, pl, Mr, Rl);
    pass2      <<<dim3(256),      256, 0, stream>>>(qh, ql, kh, kl, vtg, Mr, Rl, part0, part1);
    merge_k    <<<dim3(2048),     256, 0, stream>>>(part0, part1, out);
}